// Round 5
// baseline (470.236 us; speedup 1.0000x reference)
//
#include <hip/hip_runtime.h>

#define N_NODES 100000
#define N_EDGES 1000000
#define N_GRAPHS 128
#define IN_DIM 32
#define HID 64
#define LAT 32
#define N_LAYERS 3

#define MPAD 68  // padded LDS row stride (floats), 16B-aligned rows

// ---- dst-bucket edge build (coalesced CSR construction) ----
#define BSZ 256                                  // nodes per bucket
#define NBK ((N_NODES + BSZ - 1) / BSZ)          // 391 buckets
#define EPB 4096                                 // edges per binsort block
                                                 // (R3: 16384 -> 62 blocks, 4.7% occ, 46us;
                                                 //  4096 -> 245 blocks ~1/CU, latency hidden)
#define NBIN_BLOCKS ((N_EDGES + EPB - 1) / EPB)  // 245

// ---------------- input projection: h = x @ w_in + b_in ----------------
__global__ __launch_bounds__(256) void proj_kernel(
    const float* __restrict__ x, const float* __restrict__ w_in,
    const float* __restrict__ b_in, float* __restrict__ h) {
    __shared__ float ws[IN_DIM * HID];   // 8 KB
    __shared__ float xs[4 * IN_DIM];
    int tid = threadIdx.x;
    for (int i = tid; i < IN_DIM * HID / 4; i += 256)
        ((float4*)ws)[i] = ((const float4*)w_in)[i];
    if (tid < 32) {
        int r = tid >> 3, c4 = tid & 7;
        int nn = blockIdx.x * 4 + r;
        float4 v = make_float4(0.f, 0.f, 0.f, 0.f);
        if (nn < N_NODES) v = ((const float4*)(x + (size_t)nn * IN_DIM))[c4];
        ((float4*)xs)[tid] = v;
    }
    __syncthreads();
    int w = tid >> 6, j = tid & 63;
    int n = blockIdx.x * 4 + w;
    if (n >= N_NODES) return;
    float acc = b_in[j];
#pragma unroll
    for (int k = 0; k < IN_DIM; k += 4) {
        float4 xv = *(const float4*)&xs[w * IN_DIM + k];
        acc += xv.x * ws[(k + 0) * HID + j];
        acc += xv.y * ws[(k + 1) * HID + j];
        acc += xv.z * ws[(k + 2) * HID + j];
        acc += xv.w * ws[(k + 3) * HID + j];
    }
    h[(size_t)n * HID + j] = acc;
}

// ---------------- bucket histogram (LDS-aggregated) ----------------
__global__ __launch_bounds__(256) void bhist_kernel(const int* __restrict__ ei,
                                                    int* __restrict__ bhist) {
    __shared__ int hs[NBK];
    for (int i = threadIdx.x; i < NBK; i += 256) hs[i] = 0;
    __syncthreads();
    int e = blockIdx.x * (256 * 16) + threadIdx.x;
#pragma unroll
    for (int k = 0; k < 16; k++, e += 256)
        if (e < N_EDGES) atomicAdd(&hs[ei[N_EDGES + e] >> 8], 1);
    __syncthreads();
    for (int i = threadIdx.x; i < NBK; i += 256) {
        int c = hs[i];
        if (c) atomicAdd(&bhist[i], c);
    }
}

// ---------------- bucket scan: bstart (exclusive) + cursor init ----------------
__global__ __launch_bounds__(512) void bscan_kernel(const int* __restrict__ bhist,
                                                    int* __restrict__ bstart,
                                                    int* __restrict__ bcursor) {
    __shared__ int sc[512];
    int tid = threadIdx.x;
    int v = (tid < NBK) ? bhist[tid] : 0;
    sc[tid] = v;
    __syncthreads();
    for (int off = 1; off < 512; off <<= 1) {
        int t = (tid >= off) ? sc[tid - off] : 0;
        __syncthreads();
        sc[tid] += t;
        __syncthreads();
    }
    if (tid < NBK) {
        int ex = sc[tid] - v;
        bstart[tid] = ex;
        bcursor[tid] = ex;
    }
    if (tid == 0) bstart[NBK] = N_EDGES;
}

// ---------------- binsort: scatter edges into bucket-major order ----------------
// Packed entry: (dst & 255) << 17 | src  (src < 2^17)
__global__ __launch_bounds__(512) void binsort_kernel(const int* __restrict__ ei,
                                                      int* __restrict__ bcursor,
                                                      int* __restrict__ tmp) {
    __shared__ int hist[NBK];
    __shared__ int lofs[NBK + 1];
    __shared__ int cur[NBK];
    __shared__ int gbase[NBK];
    __shared__ int sc[512];
    __shared__ int stage[EPB];   // 16 KB
    int tid = threadIdx.x;
    int e0 = blockIdx.x * EPB;
    int nE = min(EPB, N_EDGES - e0);
    for (int i = tid; i < NBK; i += 512) hist[i] = 0;
    __syncthreads();
    // local count
    for (int i = tid; i < nE; i += 512)
        atomicAdd(&hist[ei[N_EDGES + e0 + i] >> 8], 1);
    __syncthreads();
    // local scan (Hillis-Steele over 512)
    int v = (tid < NBK) ? hist[tid] : 0;
    sc[tid] = v;
    __syncthreads();
    for (int off = 1; off < 512; off <<= 1) {
        int t = (tid >= off) ? sc[tid - off] : 0;
        __syncthreads();
        sc[tid] += t;
        __syncthreads();
    }
    if (tid < NBK) {
        int ex = sc[tid] - v;
        lofs[tid] = ex;
        cur[tid] = ex;
        gbase[tid] = atomicAdd(&bcursor[tid], v);  // one reserve per bucket
    }
    if (tid == 0) lofs[NBK] = nE;
    __syncthreads();
    // local place (group by bucket in LDS; edges L2-hot from count pass)
    for (int i = tid; i < nE; i += 512) {
        int s = ei[e0 + i];
        int d = ei[N_EDGES + e0 + i];
        int b = d >> 8;
        int p = atomicAdd(&cur[b], 1);
        stage[p] = ((d & 255) << 17) | s;
    }
    __syncthreads();
    // coalesced run copy-out; bucket of position i via binary search in lofs
    for (int i = tid; i < nE; i += 512) {
        int pv = stage[i];
        int lo = 0, hi = NBK;   // invariant: lofs[lo] <= i < lofs[hi]
        while (hi - lo > 1) {
            int mid = (lo + hi) >> 1;
            if (lofs[mid] <= i) lo = mid; else hi = mid;
        }
        tmp[gbase[lo] + (i - lofs[lo])] = pv;
    }
}

// ---------------- CSR finalize: per-bucket node sort ----------------
__global__ __launch_bounds__(256) void csr_finalize_kernel(
    const int* __restrict__ bstart, const int* __restrict__ tmp,
    int* __restrict__ srcs, int* __restrict__ offsets) {
    __shared__ int cnt[BSZ];
    __shared__ int ofs[BSZ];
    __shared__ int cur[BSZ];
    int b = blockIdx.x, tid = threadIdx.x;
    int beg = bstart[b], end = bstart[b + 1];
    cnt[tid] = 0;
    __syncthreads();
    for (int i = beg + tid; i < end; i += 256)
        atomicAdd(&cnt[tmp[i] >> 17], 1);
    __syncthreads();
    int v = cnt[tid];
    ofs[tid] = v;
    __syncthreads();
    for (int off = 1; off < 256; off <<= 1) {
        int t = (tid >= off) ? ofs[tid - off] : 0;
        __syncthreads();
        ofs[tid] += t;
        __syncthreads();
    }
    int ex = ofs[tid] - v;
    cur[tid] = ex;
    int n = b * BSZ + tid;
    if (n < N_NODES) {
        offsets[n] = beg + ex;
        if (n == N_NODES - 1) offsets[N_NODES] = beg + ex + v;
    }
    __syncthreads();
    for (int i = beg + tid; i < end; i += 256) {
        int pv = tmp[i];
        int p = atomicAdd(&cur[pv >> 17], 1);
        srcs[beg + p] = pv & 0x1FFFF;
    }
}

// ---------------- fused GIN layer: gather + MLP, hin -> hout ----------------
// Block = 64 nodes, 512 threads. Phase 1: 8 waves gather 8 nodes each
// (one-wave-per-node shfl pattern, lane j = feature j) writing m = h+agg
// straight into the ms LDS tile — agg array eliminated. Phase 2/3: 2x4
// register micro-tile GEMMs. Memory-stalled gather of one block overlaps
// VALU-bound GEMM of co-resident blocks (3 blocks/CU at 49KB LDS).
// hin/hout double-buffered across layers (blocks read random hin rows).
__global__ __launch_bounds__(512) void gin_layer_kernel(
    const float* __restrict__ hin, float* __restrict__ hout,
    const int* __restrict__ offsets, const int* __restrict__ srcs,
    const float* __restrict__ w1, const float* __restrict__ b1,
    const float* __restrict__ w2, const float* __restrict__ b2) {
    __shared__ float w1s[HID * HID];   // 16 KB
    __shared__ float w2s[HID * HID];   // 16 KB
    __shared__ float ms[64 * MPAD];    // 17 KB, reused for t
    int tid = threadIdx.x;
    int row0 = blockIdx.x * 64;
    for (int i = tid; i < HID * HID / 4; i += 512) {
        ((float4*)w1s)[i] = ((const float4*)w1)[i];
        ((float4*)w2s)[i] = ((const float4*)w2)[i];
    }

    // ---- gather phase ----
    int w = tid >> 6, j = tid & 63;
#pragma unroll 1
    for (int r = w * 8; r < w * 8 + 8; r++) {
        int n = row0 + r;
        float acc0 = 0.f, acc1 = 0.f, acc2 = 0.f, acc3 = 0.f;
        float hv = 0.f;
        if (n < N_NODES) {
            hv = hin[(size_t)n * HID + j];
            int beg = offsets[n], end = offsets[n + 1];
            for (int c = beg; c < end; c += 64) {
                int myS = (c + j < end) ? srcs[c + j] : 0;
                int m = min(64, end - c);
                int i = 0;
                for (; i + 3 < m; i += 4) {
                    int s0 = __shfl(myS, i);
                    int s1 = __shfl(myS, i + 1);
                    int s2 = __shfl(myS, i + 2);
                    int s3 = __shfl(myS, i + 3);
                    acc0 += hin[(size_t)s0 * HID + j];
                    acc1 += hin[(size_t)s1 * HID + j];
                    acc2 += hin[(size_t)s2 * HID + j];
                    acc3 += hin[(size_t)s3 * HID + j];
                }
                for (; i < m; i++) acc0 += hin[(size_t)__shfl(myS, i) * HID + j];
            }
        }
        ms[r * MPAD + j] = hv + acc0 + acc1 + acc2 + acc3;
    }
    __syncthreads();

    // ---- MLP phase ----
    int ty = tid >> 4, tx = tid & 15;   // ty 0..31, tx 0..15
    int r0 = ty * 2, c0 = tx * 4;

    float4 a0, a1;
#define GEMM_LDS(WS)                                                          \
    do {                                                                      \
        a0 = make_float4(0.f, 0.f, 0.f, 0.f); a1 = a0;                        \
        _Pragma("unroll 4")                                                   \
        for (int k0 = 0; k0 < HID; k0 += 4) {                                 \
            float4 m0 = *(const float4*)&ms[(r0 + 0) * MPAD + k0];            \
            float4 m1 = *(const float4*)&ms[(r0 + 1) * MPAD + k0];            \
            float4 w0 = *(const float4*)&WS[(k0 + 0) * HID + c0];             \
            float4 w1v = *(const float4*)&WS[(k0 + 1) * HID + c0];            \
            float4 w2v = *(const float4*)&WS[(k0 + 2) * HID + c0];            \
            float4 w3v = *(const float4*)&WS[(k0 + 3) * HID + c0];            \
            a0.x += m0.x * w0.x + m0.y * w1v.x + m0.z * w2v.x + m0.w * w3v.x; \
            a0.y += m0.x * w0.y + m0.y * w1v.y + m0.z * w2v.y + m0.w * w3v.y; \
            a0.z += m0.x * w0.z + m0.y * w1v.z + m0.z * w2v.z + m0.w * w3v.z; \
            a0.w += m0.x * w0.w + m0.y * w1v.w + m0.z * w2v.w + m0.w * w3v.w; \
            a1.x += m1.x * w0.x + m1.y * w1v.x + m1.z * w2v.x + m1.w * w3v.x; \
            a1.y += m1.x * w0.y + m1.y * w1v.y + m1.z * w2v.y + m1.w * w3v.y; \
            a1.z += m1.x * w0.z + m1.y * w1v.z + m1.z * w2v.z + m1.w * w3v.z; \
            a1.w += m1.x * w0.w + m1.y * w1v.w + m1.z * w2v.w + m1.w * w3v.w; \
        }                                                                     \
    } while (0)

    GEMM_LDS(w1s);  // GEMM1

    float4 bv1 = *(const float4*)&b1[c0];
    float4 t0 = make_float4(fmaxf(a0.x + bv1.x, 0.f), fmaxf(a0.y + bv1.y, 0.f),
                            fmaxf(a0.z + bv1.z, 0.f), fmaxf(a0.w + bv1.w, 0.f));
    float4 t1 = make_float4(fmaxf(a1.x + bv1.x, 0.f), fmaxf(a1.y + bv1.y, 0.f),
                            fmaxf(a1.z + bv1.z, 0.f), fmaxf(a1.w + bv1.w, 0.f));

    __syncthreads();  // all GEMM1 reads of ms complete
    *(float4*)&ms[(r0 + 0) * MPAD + c0] = t0;
    *(float4*)&ms[(r0 + 1) * MPAD + c0] = t1;
    __syncthreads();

    GEMM_LDS(w2s);  // GEMM2

    float4 bv2 = *(const float4*)&b2[c0];
#pragma unroll
    for (int i = 0; i < 2; i++) {
        int n = row0 + r0 + i;
        if (n < N_NODES) {
            float4 av = (i == 0) ? a0 : a1;
            float4 hold = *(const float4*)(hin + (size_t)n * HID + c0);
            float4 o;
            o.x = fmaxf(av.x + bv2.x, 0.f) + hold.x;
            o.y = fmaxf(av.y + bv2.y, 0.f) + hold.y;
            o.z = fmaxf(av.z + bv2.z, 0.f) + hold.z;
            o.w = fmaxf(av.w + bv2.w, 0.f) + hold.w;
            *(float4*)(hout + (size_t)n * HID + c0) = o;
        }
    }
#undef GEMM_LDS
}

// ---------------- global add pool ----------------
__global__ __launch_bounds__(256) void pool_kernel(
    const float* __restrict__ h, const int* __restrict__ batch,
    float* __restrict__ pooled) {
    int tid = threadIdx.x;
    int w = tid >> 6, j = tid & 63;
    int n0 = blockIdx.x * 256 + w * 64;
    if (n0 >= N_NODES) return;
    int nend = min(n0 + 64, N_NODES);
    float acc = 0.f;
    int cur = batch[n0];
    for (int n = n0; n < nend; n++) {
        int b = batch[n];
        if (b != cur) {
            atomicAdd(&pooled[cur * HID + j], acc);
            acc = 0.f;
            cur = b;
        }
        acc += h[(size_t)n * HID + j];
    }
    atomicAdd(&pooled[cur * HID + j], acc);
}

// ---------------- final FC ----------------
__global__ __launch_bounds__(256) void final_kernel(
    const float* __restrict__ pooled, const float* __restrict__ w_fc,
    const float* __restrict__ b_fc, float* __restrict__ out) {
    int gid = blockIdx.x * 256 + threadIdx.x;
    if (gid >= N_GRAPHS * LAT) return;
    int g = gid >> 5, j = gid & 31;
    float acc = b_fc[j];
#pragma unroll
    for (int k = 0; k < HID; k++)
        acc += pooled[g * HID + k] * w_fc[k * LAT + j];
    out[gid] = acc;
}

extern "C" void kernel_launch(void* const* d_in, const int* in_sizes, int n_in,
                              void* d_out, int out_size, void* d_ws,
                              size_t ws_size, hipStream_t stream) {
    const float* x     = (const float*)d_in[0];
    const int*   ei    = (const int*)d_in[1];
    const int*   batch = (const int*)d_in[2];
    const float* w_in  = (const float*)d_in[3];
    const float* b_in  = (const float*)d_in[4];
    const float* w1    = (const float*)d_in[5];
    const float* b1    = (const float*)d_in[6];
    const float* w2    = (const float*)d_in[7];
    const float* b2    = (const float*)d_in[8];
    const float* w_fc  = (const float*)d_in[9];
    const float* b_fc  = (const float*)d_in[10];
    float* out = (float*)d_out;

    // persistent: h | h2 | pooled | offsets | srcs   (~55.6 MB)
    float* h       = (float*)d_ws;
    float* h2      = h + (size_t)N_NODES * HID;
    float* pooled  = h2 + (size_t)N_NODES * HID;
    int*   offsets = (int*)(pooled + N_GRAPHS * HID);   // N_NODES+1
    int*   srcs    = offsets + (N_NODES + 2);           // N_EDGES
    // build-time arrays overlaid into h2's region (dead until layer 0 writes)
    int* tmp     = (int*)h2;             // N_EDGES packed bucket-major edges
    int* bhist   = tmp + N_EDGES;        // NBK
    int* bstart  = bhist + NBK;          // NBK + 1
    int* bcursor = bstart + (NBK + 1);   // NBK

    proj_kernel<<<(N_NODES + 3) / 4, 256, 0, stream>>>(x, w_in, b_in, h);

    // coalesced CSR build (once; edges constant across layers)
    hipMemsetAsync(bhist, 0, NBK * sizeof(int), stream);
    bhist_kernel<<<(N_EDGES + 4095) / 4096, 256, 0, stream>>>(ei, bhist);
    bscan_kernel<<<1, 512, 0, stream>>>(bhist, bstart, bcursor);
    binsort_kernel<<<NBIN_BLOCKS, 512, 0, stream>>>(ei, bcursor, tmp);
    csr_finalize_kernel<<<NBK, 256, 0, stream>>>(bstart, tmp, srcs, offsets);

    // fused layers, h ping-pong: h -> h2 -> h -> h2
    float* hin = h;
    float* hout = h2;
    for (int i = 0; i < N_LAYERS; i++) {
        gin_layer_kernel<<<(N_NODES + 63) / 64, 512, 0, stream>>>(
            hin, hout, offsets, srcs, w1 + (size_t)i * HID * HID,
            b1 + (size_t)i * HID, w2 + (size_t)i * HID * HID,
            b2 + (size_t)i * HID);
        float* t = hin; hin = hout; hout = t;
    }
    // final features are in hin after the swap

    hipMemsetAsync(pooled, 0, N_GRAPHS * HID * sizeof(float), stream);
    pool_kernel<<<(N_NODES + 255) / 256, 256, 0, stream>>>(hin, batch, pooled);
    final_kernel<<<(N_GRAPHS * LAT + 255) / 256, 256, 0, stream>>>(
        pooled, w_fc, b_fc, out);
}

// Round 6
// 429.352 us; speedup vs baseline: 1.0952x; 1.0952x over previous
//
#include <hip/hip_runtime.h>

#define N_NODES 100000
#define N_EDGES 1000000
#define N_GRAPHS 128
#define IN_DIM 32
#define HID 64
#define LAT 32
#define N_LAYERS 3

#define MPAD 68    // padded LDS row stride (floats), 16B-aligned rows
#define MTILE 128  // nodes per mlp block (4x4 micro-tile, 512 threads)

// ---- dst-bucket edge build (coalesced CSR construction) ----
#define BSZ 256                                  // nodes per bucket
#define NBK ((N_NODES + BSZ - 1) / BSZ)          // 391 buckets
#define EPB 4096                                 // edges per binsort block
                                                 // (R3: 16384 -> 62 blocks, 4.7% occ, 46us;
                                                 //  4096 -> 245 blocks ~1/CU, latency hidden)
#define NBIN_BLOCKS ((N_EDGES + EPB - 1) / EPB)  // 245

// R5 lesson: do NOT fuse gather into the MLP kernel. Fused version dropped
// occupancy to 35% (50KB LDS) and co-resident blocks hit the barrier-split
// phases in lockstep -> phases serialized at half the memory parallelism
// (1.5 vs 3.25 TB/s). Split kernels: gather gets max TLP, mlp gets LDS BW.

// ---------------- input projection: h = x @ w_in + b_in ----------------
__global__ __launch_bounds__(256) void proj_kernel(
    const float* __restrict__ x, const float* __restrict__ w_in,
    const float* __restrict__ b_in, float* __restrict__ h) {
    __shared__ float ws[IN_DIM * HID];   // 8 KB
    __shared__ float xs[4 * IN_DIM];
    int tid = threadIdx.x;
    for (int i = tid; i < IN_DIM * HID / 4; i += 256)
        ((float4*)ws)[i] = ((const float4*)w_in)[i];
    if (tid < 32) {
        int r = tid >> 3, c4 = tid & 7;
        int nn = blockIdx.x * 4 + r;
        float4 v = make_float4(0.f, 0.f, 0.f, 0.f);
        if (nn < N_NODES) v = ((const float4*)(x + (size_t)nn * IN_DIM))[c4];
        ((float4*)xs)[tid] = v;
    }
    __syncthreads();
    int w = tid >> 6, j = tid & 63;
    int n = blockIdx.x * 4 + w;
    if (n >= N_NODES) return;
    float acc = b_in[j];
#pragma unroll
    for (int k = 0; k < IN_DIM; k += 4) {
        float4 xv = *(const float4*)&xs[w * IN_DIM + k];
        acc += xv.x * ws[(k + 0) * HID + j];
        acc += xv.y * ws[(k + 1) * HID + j];
        acc += xv.z * ws[(k + 2) * HID + j];
        acc += xv.w * ws[(k + 3) * HID + j];
    }
    h[(size_t)n * HID + j] = acc;
}

// ---------------- bucket histogram (LDS-aggregated) ----------------
__global__ __launch_bounds__(256) void bhist_kernel(const int* __restrict__ ei,
                                                    int* __restrict__ bhist) {
    __shared__ int hs[NBK];
    for (int i = threadIdx.x; i < NBK; i += 256) hs[i] = 0;
    __syncthreads();
    int e = blockIdx.x * (256 * 16) + threadIdx.x;
#pragma unroll
    for (int k = 0; k < 16; k++, e += 256)
        if (e < N_EDGES) atomicAdd(&hs[ei[N_EDGES + e] >> 8], 1);
    __syncthreads();
    for (int i = threadIdx.x; i < NBK; i += 256) {
        int c = hs[i];
        if (c) atomicAdd(&bhist[i], c);
    }
}

// ---------------- bucket scan: bstart (exclusive) + cursor init ----------------
__global__ __launch_bounds__(512) void bscan_kernel(const int* __restrict__ bhist,
                                                    int* __restrict__ bstart,
                                                    int* __restrict__ bcursor) {
    __shared__ int sc[512];
    int tid = threadIdx.x;
    int v = (tid < NBK) ? bhist[tid] : 0;
    sc[tid] = v;
    __syncthreads();
    for (int off = 1; off < 512; off <<= 1) {
        int t = (tid >= off) ? sc[tid - off] : 0;
        __syncthreads();
        sc[tid] += t;
        __syncthreads();
    }
    if (tid < NBK) {
        int ex = sc[tid] - v;
        bstart[tid] = ex;
        bcursor[tid] = ex;
    }
    if (tid == 0) bstart[NBK] = N_EDGES;
}

// ---------------- binsort: scatter edges into bucket-major order ----------------
// Packed entry: (dst & 255) << 17 | src  (src < 2^17)
__global__ __launch_bounds__(512) void binsort_kernel(const int* __restrict__ ei,
                                                      int* __restrict__ bcursor,
                                                      int* __restrict__ tmp) {
    __shared__ int hist[NBK];
    __shared__ int lofs[NBK + 1];
    __shared__ int cur[NBK];
    __shared__ int gbase[NBK];
    __shared__ int sc[512];
    __shared__ int stage[EPB];   // 16 KB
    int tid = threadIdx.x;
    int e0 = blockIdx.x * EPB;
    int nE = min(EPB, N_EDGES - e0);
    for (int i = tid; i < NBK; i += 512) hist[i] = 0;
    __syncthreads();
    // local count
    for (int i = tid; i < nE; i += 512)
        atomicAdd(&hist[ei[N_EDGES + e0 + i] >> 8], 1);
    __syncthreads();
    // local scan (Hillis-Steele over 512)
    int v = (tid < NBK) ? hist[tid] : 0;
    sc[tid] = v;
    __syncthreads();
    for (int off = 1; off < 512; off <<= 1) {
        int t = (tid >= off) ? sc[tid - off] : 0;
        __syncthreads();
        sc[tid] += t;
        __syncthreads();
    }
    if (tid < NBK) {
        int ex = sc[tid] - v;
        lofs[tid] = ex;
        cur[tid] = ex;
        gbase[tid] = atomicAdd(&bcursor[tid], v);  // one reserve per bucket
    }
    if (tid == 0) lofs[NBK] = nE;
    __syncthreads();
    // local place (group by bucket in LDS; edges L2-hot from count pass)
    for (int i = tid; i < nE; i += 512) {
        int s = ei[e0 + i];
        int d = ei[N_EDGES + e0 + i];
        int b = d >> 8;
        int p = atomicAdd(&cur[b], 1);
        stage[p] = ((d & 255) << 17) | s;
    }
    __syncthreads();
    // coalesced run copy-out; bucket of position i via binary search in lofs
    for (int i = tid; i < nE; i += 512) {
        int pv = stage[i];
        int lo = 0, hi = NBK;   // invariant: lofs[lo] <= i < lofs[hi]
        while (hi - lo > 1) {
            int mid = (lo + hi) >> 1;
            if (lofs[mid] <= i) lo = mid; else hi = mid;
        }
        tmp[gbase[lo] + (i - lofs[lo])] = pv;
    }
}

// ---------------- CSR finalize: per-bucket node sort ----------------
__global__ __launch_bounds__(256) void csr_finalize_kernel(
    const int* __restrict__ bstart, const int* __restrict__ tmp,
    int* __restrict__ srcs, int* __restrict__ offsets) {
    __shared__ int cnt[BSZ];
    __shared__ int ofs[BSZ];
    __shared__ int cur[BSZ];
    int b = blockIdx.x, tid = threadIdx.x;
    int beg = bstart[b], end = bstart[b + 1];
    cnt[tid] = 0;
    __syncthreads();
    for (int i = beg + tid; i < end; i += 256)
        atomicAdd(&cnt[tmp[i] >> 17], 1);
    __syncthreads();
    int v = cnt[tid];
    ofs[tid] = v;
    __syncthreads();
    for (int off = 1; off < 256; off <<= 1) {
        int t = (tid >= off) ? ofs[tid - off] : 0;
        __syncthreads();
        ofs[tid] += t;
        __syncthreads();
    }
    int ex = ofs[tid] - v;
    cur[tid] = ex;
    int n = b * BSZ + tid;
    if (n < N_NODES) {
        offsets[n] = beg + ex;
        if (n == N_NODES - 1) offsets[N_NODES] = beg + ex + v;
    }
    __syncthreads();
    for (int i = beg + tid; i < end; i += 256) {
        int pv = tmp[i];
        int p = atomicAdd(&cur[pv >> 17], 1);
        srcs[beg + p] = pv & 0x1FFFF;
    }
}

// ---------------- gather: agg[n] = sum_{e in in(n)} h[src[e]] ----------------
// one wave per node (100K waves -> latency hidden by TLP); lane j owns
// feature j; 8 independent load chains for MLP (deg~10 -> one 8-group +
// remainder instead of 4+4+2 waitcnt groups).
__global__ __launch_bounds__(256) void gather_kernel(
    const int* __restrict__ offsets, const int* __restrict__ srcs,
    const float* __restrict__ h, float* __restrict__ agg) {
    int w = threadIdx.x >> 6, j = threadIdx.x & 63;
    int n = blockIdx.x * 4 + w;
    if (n >= N_NODES) return;
    int beg = offsets[n], end = offsets[n + 1];
    float acc0 = 0.f, acc1 = 0.f, acc2 = 0.f, acc3 = 0.f;
    float acc4 = 0.f, acc5 = 0.f, acc6 = 0.f, acc7 = 0.f;
    for (int c = beg; c < end; c += 64) {
        int myS = (c + j < end) ? srcs[c + j] : 0;
        int m = min(64, end - c);
        int i = 0;
        for (; i + 7 < m; i += 8) {
            int s0 = __shfl(myS, i);
            int s1 = __shfl(myS, i + 1);
            int s2 = __shfl(myS, i + 2);
            int s3 = __shfl(myS, i + 3);
            int s4 = __shfl(myS, i + 4);
            int s5 = __shfl(myS, i + 5);
            int s6 = __shfl(myS, i + 6);
            int s7 = __shfl(myS, i + 7);
            acc0 += h[(size_t)s0 * HID + j];
            acc1 += h[(size_t)s1 * HID + j];
            acc2 += h[(size_t)s2 * HID + j];
            acc3 += h[(size_t)s3 * HID + j];
            acc4 += h[(size_t)s4 * HID + j];
            acc5 += h[(size_t)s5 * HID + j];
            acc6 += h[(size_t)s6 * HID + j];
            acc7 += h[(size_t)s7 * HID + j];
        }
        for (; i + 3 < m; i += 4) {
            int s0 = __shfl(myS, i);
            int s1 = __shfl(myS, i + 1);
            int s2 = __shfl(myS, i + 2);
            int s3 = __shfl(myS, i + 3);
            acc0 += h[(size_t)s0 * HID + j];
            acc1 += h[(size_t)s1 * HID + j];
            acc2 += h[(size_t)s2 * HID + j];
            acc3 += h[(size_t)s3 * HID + j];
        }
        for (; i < m; i++) acc0 += h[(size_t)__shfl(myS, i) * HID + j];
    }
    agg[(size_t)n * HID + j] =
        (acc0 + acc1) + (acc2 + acc3) + ((acc4 + acc5) + (acc6 + acc7));
}

// ---------------- fused GIN MLP ----------------
// 512 threads, 128-node tile, 4x4 register micro-tile (16 accs).
// LDS bytes per 128 FLOP: 4 m-float4 + 4 w-float4 = 128 B -> 1.0 FLOP/B
// (old 2x4 tile: 0.67) — mlp was LDS-BW-bound at ~36us/layer.
// LDS 67 KB -> 2 blocks/CU = 16 waves/CU; 16 indep FMA chains feed VALU.
__global__ __launch_bounds__(512) void mlp_kernel(
    float* __restrict__ h, const float* __restrict__ agg,
    const float* __restrict__ w1, const float* __restrict__ b1,
    const float* __restrict__ w2, const float* __restrict__ b2) {
    __shared__ float w1s[HID * HID];    // 16 KB
    __shared__ float w2s[HID * HID];    // 16 KB
    __shared__ float ms[MTILE * MPAD];  // 34 KB, reused for t
    int tid = threadIdx.x;
    int row0 = blockIdx.x * MTILE;
    for (int i = tid; i < HID * HID / 4; i += 512) {
        ((float4*)w1s)[i] = ((const float4*)w1)[i];
        ((float4*)w2s)[i] = ((const float4*)w2)[i];
    }
#pragma unroll
    for (int i = 0; i < 4; i++) {
        int f = tid + i * 512;
        int r = f >> 4, c4 = f & 15;
        int n = row0 + r;
        float4 mv = make_float4(0.f, 0.f, 0.f, 0.f);
        if (n < N_NODES) {
            float4 h4 = ((const float4*)(h + (size_t)n * HID))[c4];
            float4 a4 = ((const float4*)(agg + (size_t)n * HID))[c4];
            mv = make_float4(h4.x + a4.x, h4.y + a4.y, h4.z + a4.z, h4.w + a4.w);
        }
        *(float4*)&ms[r * MPAD + c4 * 4] = mv;
    }
    __syncthreads();

    int ty = tid >> 4, tx = tid & 15;   // ty 0..31, tx 0..15
    int r0 = ty * 4, c0 = tx * 4;

    float4 a0, a1, a2, a3;
#define GEMM_LDS(WS)                                                          \
    do {                                                                      \
        a0 = make_float4(0.f, 0.f, 0.f, 0.f); a1 = a0; a2 = a0; a3 = a0;      \
        _Pragma("unroll 4")                                                   \
        for (int k0 = 0; k0 < HID; k0 += 4) {                                 \
            float4 m0 = *(const float4*)&ms[(r0 + 0) * MPAD + k0];            \
            float4 m1 = *(const float4*)&ms[(r0 + 1) * MPAD + k0];            \
            float4 m2 = *(const float4*)&ms[(r0 + 2) * MPAD + k0];            \
            float4 m3 = *(const float4*)&ms[(r0 + 3) * MPAD + k0];            \
            float4 w0 = *(const float4*)&WS[(k0 + 0) * HID + c0];             \
            float4 w1v = *(const float4*)&WS[(k0 + 1) * HID + c0];            \
            float4 w2v = *(const float4*)&WS[(k0 + 2) * HID + c0];            \
            float4 w3v = *(const float4*)&WS[(k0 + 3) * HID + c0];            \
            a0.x += m0.x * w0.x + m0.y * w1v.x + m0.z * w2v.x + m0.w * w3v.x; \
            a0.y += m0.x * w0.y + m0.y * w1v.y + m0.z * w2v.y + m0.w * w3v.y; \
            a0.z += m0.x * w0.z + m0.y * w1v.z + m0.z * w2v.z + m0.w * w3v.z; \
            a0.w += m0.x * w0.w + m0.y * w1v.w + m0.z * w2v.w + m0.w * w3v.w; \
            a1.x += m1.x * w0.x + m1.y * w1v.x + m1.z * w2v.x + m1.w * w3v.x; \
            a1.y += m1.x * w0.y + m1.y * w1v.y + m1.z * w2v.y + m1.w * w3v.y; \
            a1.z += m1.x * w0.z + m1.y * w1v.z + m1.z * w2v.z + m1.w * w3v.z; \
            a1.w += m1.x * w0.w + m1.y * w1v.w + m1.z * w2v.w + m1.w * w3v.w; \
            a2.x += m2.x * w0.x + m2.y * w1v.x + m2.z * w2v.x + m2.w * w3v.x; \
            a2.y += m2.x * w0.y + m2.y * w1v.y + m2.z * w2v.y + m2.w * w3v.y; \
            a2.z += m2.x * w0.z + m2.y * w1v.z + m2.z * w2v.z + m2.w * w3v.z; \
            a2.w += m2.x * w0.w + m2.y * w1v.w + m2.z * w2v.w + m2.w * w3v.w; \
            a3.x += m3.x * w0.x + m3.y * w1v.x + m3.z * w2v.x + m3.w * w3v.x; \
            a3.y += m3.x * w0.y + m3.y * w1v.y + m3.z * w2v.y + m3.w * w3v.y; \
            a3.z += m3.x * w0.z + m3.y * w1v.z + m3.z * w2v.z + m3.w * w3v.z; \
            a3.w += m3.x * w0.w + m3.y * w1v.w + m3.z * w2v.w + m3.w * w3v.w; \
        }                                                                     \
    } while (0)

    GEMM_LDS(w1s);  // GEMM1

    float4 bv1 = *(const float4*)&b1[c0];
    float4 t0 = make_float4(fmaxf(a0.x + bv1.x, 0.f), fmaxf(a0.y + bv1.y, 0.f),
                            fmaxf(a0.z + bv1.z, 0.f), fmaxf(a0.w + bv1.w, 0.f));
    float4 t1 = make_float4(fmaxf(a1.x + bv1.x, 0.f), fmaxf(a1.y + bv1.y, 0.f),
                            fmaxf(a1.z + bv1.z, 0.f), fmaxf(a1.w + bv1.w, 0.f));
    float4 t2 = make_float4(fmaxf(a2.x + bv1.x, 0.f), fmaxf(a2.y + bv1.y, 0.f),
                            fmaxf(a2.z + bv1.z, 0.f), fmaxf(a2.w + bv1.w, 0.f));
    float4 t3 = make_float4(fmaxf(a3.x + bv1.x, 0.f), fmaxf(a3.y + bv1.y, 0.f),
                            fmaxf(a3.z + bv1.z, 0.f), fmaxf(a3.w + bv1.w, 0.f));

    __syncthreads();  // all GEMM1 reads of ms complete
    *(float4*)&ms[(r0 + 0) * MPAD + c0] = t0;
    *(float4*)&ms[(r0 + 1) * MPAD + c0] = t1;
    *(float4*)&ms[(r0 + 2) * MPAD + c0] = t2;
    *(float4*)&ms[(r0 + 3) * MPAD + c0] = t3;
    __syncthreads();

    GEMM_LDS(w2s);  // GEMM2

    float4 bv2 = *(const float4*)&b2[c0];
#pragma unroll
    for (int i = 0; i < 4; i++) {
        int n = row0 + r0 + i;
        if (n < N_NODES) {
            float4 av = (i == 0) ? a0 : (i == 1) ? a1 : (i == 2) ? a2 : a3;
            float4 hold = *(const float4*)(h + (size_t)n * HID + c0);
            float4 o;
            o.x = fmaxf(av.x + bv2.x, 0.f) + hold.x;
            o.y = fmaxf(av.y + bv2.y, 0.f) + hold.y;
            o.z = fmaxf(av.z + bv2.z, 0.f) + hold.z;
            o.w = fmaxf(av.w + bv2.w, 0.f) + hold.w;
            *(float4*)(h + (size_t)n * HID + c0) = o;
        }
    }
#undef GEMM_LDS
}

// ---------------- global add pool ----------------
__global__ __launch_bounds__(256) void pool_kernel(
    const float* __restrict__ h, const int* __restrict__ batch,
    float* __restrict__ pooled) {
    int tid = threadIdx.x;
    int w = tid >> 6, j = tid & 63;
    int n0 = blockIdx.x * 256 + w * 64;
    if (n0 >= N_NODES) return;
    int nend = min(n0 + 64, N_NODES);
    float acc = 0.f;
    int cur = batch[n0];
    for (int n = n0; n < nend; n++) {
        int b = batch[n];
        if (b != cur) {
            atomicAdd(&pooled[cur * HID + j], acc);
            acc = 0.f;
            cur = b;
        }
        acc += h[(size_t)n * HID + j];
    }
    atomicAdd(&pooled[cur * HID + j], acc);
}

// ---------------- final FC ----------------
__global__ __launch_bounds__(256) void final_kernel(
    const float* __restrict__ pooled, const float* __restrict__ w_fc,
    const float* __restrict__ b_fc, float* __restrict__ out) {
    int gid = blockIdx.x * 256 + threadIdx.x;
    if (gid >= N_GRAPHS * LAT) return;
    int g = gid >> 5, j = gid & 31;
    float acc = b_fc[j];
#pragma unroll
    for (int k = 0; k < HID; k++)
        acc += pooled[g * HID + k] * w_fc[k * LAT + j];
    out[gid] = acc;
}

extern "C" void kernel_launch(void* const* d_in, const int* in_sizes, int n_in,
                              void* d_out, int out_size, void* d_ws,
                              size_t ws_size, hipStream_t stream) {
    const float* x     = (const float*)d_in[0];
    const int*   ei    = (const int*)d_in[1];
    const int*   batch = (const int*)d_in[2];
    const float* w_in  = (const float*)d_in[3];
    const float* b_in  = (const float*)d_in[4];
    const float* w1    = (const float*)d_in[5];
    const float* b1    = (const float*)d_in[6];
    const float* w2    = (const float*)d_in[7];
    const float* b2    = (const float*)d_in[8];
    const float* w_fc  = (const float*)d_in[9];
    const float* b_fc  = (const float*)d_in[10];
    float* out = (float*)d_out;

    // persistent: h | agg | pooled | offsets | srcs   (~55.6 MB)
    float* h       = (float*)d_ws;
    float* agg     = h + (size_t)N_NODES * HID;
    float* pooled  = agg + (size_t)N_NODES * HID;
    int*   offsets = (int*)(pooled + N_GRAPHS * HID);   // N_NODES+1
    int*   srcs    = offsets + (N_NODES + 2);           // N_EDGES
    // build-time arrays overlaid into agg's region (dead before first gather)
    int* tmp     = (int*)agg;            // N_EDGES packed bucket-major edges
    int* bhist   = tmp + N_EDGES;        // NBK
    int* bstart  = bhist + NBK;          // NBK + 1
    int* bcursor = bstart + (NBK + 1);   // NBK

    proj_kernel<<<(N_NODES + 3) / 4, 256, 0, stream>>>(x, w_in, b_in, h);

    // coalesced CSR build (once; edges constant across layers)
    hipMemsetAsync(bhist, 0, NBK * sizeof(int), stream);
    bhist_kernel<<<(N_EDGES + 4095) / 4096, 256, 0, stream>>>(ei, bhist);
    bscan_kernel<<<1, 512, 0, stream>>>(bhist, bstart, bcursor);
    binsort_kernel<<<NBIN_BLOCKS, 512, 0, stream>>>(ei, bcursor, tmp);
    csr_finalize_kernel<<<NBK, 256, 0, stream>>>(bstart, tmp, srcs, offsets);

    for (int i = 0; i < N_LAYERS; i++) {
        gather_kernel<<<(N_NODES + 3) / 4, 256, 0, stream>>>(offsets, srcs, h, agg);
        mlp_kernel<<<(N_NODES + MTILE - 1) / MTILE, 512, 0, stream>>>(
            h, agg, w1 + (size_t)i * HID * HID, b1 + (size_t)i * HID,
            w2 + (size_t)i * HID * HID, b2 + (size_t)i * HID);
    }

    hipMemsetAsync(pooled, 0, N_GRAPHS * HID * sizeof(float), stream);
    pool_kernel<<<(N_NODES + 255) / 256, 256, 0, stream>>>(h, batch, pooled);
    final_kernel<<<(N_GRAPHS * LAT + 255) / 256, 256, 0, stream>>>(
        pooled, w_fc, b_fc, out);
}

// Round 7
// 408.927 us; speedup vs baseline: 1.1499x; 1.0499x over previous
//
#include <hip/hip_runtime.h>

#define N_NODES 100000
#define N_EDGES 1000000
#define N_GRAPHS 128
#define IN_DIM 32
#define HID 64
#define LAT 32
#define N_LAYERS 3

#define MPAD 68  // padded LDS row stride (floats), 16B-aligned rows

// ---- dst-bucket edge build (coalesced CSR construction) ----
#define BSZ 256                                  // nodes per bucket
#define NBK ((N_NODES + BSZ - 1) / BSZ)          // 391 buckets
#define EPB 4096                                 // edges per binsort block
                                                 // (R3: 16384 -> 62 blocks, 4.7% occ, 46us;
                                                 //  4096 -> 245 blocks ~1/CU, latency hidden)
#define NBIN_BLOCKS ((N_EDGES + EPB - 1) / EPB)  // 245

// R5 lesson: do NOT fuse gather into the MLP kernel (lockstep phases serialize
// at half the memory parallelism). R6 lesson: do NOT grow the mlp micro-tile
// to 4x4/128 nodes (67KB LDS -> 2 blocks/CU + grid tail -> 16.7% occupancy,
// 36->50us). 2x4/64-node tile at 3 blocks/CU is the sweet spot.

// ---------------- input projection: h = x @ w_in + b_in ----------------
__global__ __launch_bounds__(256) void proj_kernel(
    const float* __restrict__ x, const float* __restrict__ w_in,
    const float* __restrict__ b_in, float* __restrict__ h) {
    __shared__ float ws[IN_DIM * HID];   // 8 KB
    __shared__ float xs[4 * IN_DIM];
    int tid = threadIdx.x;
    for (int i = tid; i < IN_DIM * HID / 4; i += 256)
        ((float4*)ws)[i] = ((const float4*)w_in)[i];
    if (tid < 32) {
        int r = tid >> 3, c4 = tid & 7;
        int nn = blockIdx.x * 4 + r;
        float4 v = make_float4(0.f, 0.f, 0.f, 0.f);
        if (nn < N_NODES) v = ((const float4*)(x + (size_t)nn * IN_DIM))[c4];
        ((float4*)xs)[tid] = v;
    }
    __syncthreads();
    int w = tid >> 6, j = tid & 63;
    int n = blockIdx.x * 4 + w;
    if (n >= N_NODES) return;
    float acc = b_in[j];
#pragma unroll
    for (int k = 0; k < IN_DIM; k += 4) {
        float4 xv = *(const float4*)&xs[w * IN_DIM + k];
        acc += xv.x * ws[(k + 0) * HID + j];
        acc += xv.y * ws[(k + 1) * HID + j];
        acc += xv.z * ws[(k + 2) * HID + j];
        acc += xv.w * ws[(k + 3) * HID + j];
    }
    h[(size_t)n * HID + j] = acc;
}

// ---------------- bucket histogram (LDS-aggregated) ----------------
__global__ __launch_bounds__(256) void bhist_kernel(const int* __restrict__ ei,
                                                    int* __restrict__ bhist) {
    __shared__ int hs[NBK];
    for (int i = threadIdx.x; i < NBK; i += 256) hs[i] = 0;
    __syncthreads();
    int e = blockIdx.x * (256 * 16) + threadIdx.x;
#pragma unroll
    for (int k = 0; k < 16; k++, e += 256)
        if (e < N_EDGES) atomicAdd(&hs[ei[N_EDGES + e] >> 8], 1);
    __syncthreads();
    for (int i = threadIdx.x; i < NBK; i += 256) {
        int c = hs[i];
        if (c) atomicAdd(&bhist[i], c);
    }
}

// ---------------- bucket scan: bstart (exclusive) + cursor init ----------------
__global__ __launch_bounds__(512) void bscan_kernel(const int* __restrict__ bhist,
                                                    int* __restrict__ bstart,
                                                    int* __restrict__ bcursor) {
    __shared__ int sc[512];
    int tid = threadIdx.x;
    int v = (tid < NBK) ? bhist[tid] : 0;
    sc[tid] = v;
    __syncthreads();
    for (int off = 1; off < 512; off <<= 1) {
        int t = (tid >= off) ? sc[tid - off] : 0;
        __syncthreads();
        sc[tid] += t;
        __syncthreads();
    }
    if (tid < NBK) {
        int ex = sc[tid] - v;
        bstart[tid] = ex;
        bcursor[tid] = ex;
    }
    if (tid == 0) bstart[NBK] = N_EDGES;
}

// ---------------- binsort: scatter edges into bucket-major order ----------------
// Packed entry: (dst & 255) << 17 | src  (src < 2^17)
__global__ __launch_bounds__(512) void binsort_kernel(const int* __restrict__ ei,
                                                      int* __restrict__ bcursor,
                                                      int* __restrict__ tmp) {
    __shared__ int hist[NBK];
    __shared__ int lofs[NBK + 1];
    __shared__ int cur[NBK];
    __shared__ int gbase[NBK];
    __shared__ int sc[512];
    __shared__ int stage[EPB];   // 16 KB
    int tid = threadIdx.x;
    int e0 = blockIdx.x * EPB;
    int nE = min(EPB, N_EDGES - e0);
    for (int i = tid; i < NBK; i += 512) hist[i] = 0;
    __syncthreads();
    // local count
    for (int i = tid; i < nE; i += 512)
        atomicAdd(&hist[ei[N_EDGES + e0 + i] >> 8], 1);
    __syncthreads();
    // local scan (Hillis-Steele over 512)
    int v = (tid < NBK) ? hist[tid] : 0;
    sc[tid] = v;
    __syncthreads();
    for (int off = 1; off < 512; off <<= 1) {
        int t = (tid >= off) ? sc[tid - off] : 0;
        __syncthreads();
        sc[tid] += t;
        __syncthreads();
    }
    if (tid < NBK) {
        int ex = sc[tid] - v;
        lofs[tid] = ex;
        cur[tid] = ex;
        gbase[tid] = atomicAdd(&bcursor[tid], v);  // one reserve per bucket
    }
    if (tid == 0) lofs[NBK] = nE;
    __syncthreads();
    // local place (group by bucket in LDS; edges L2-hot from count pass)
    for (int i = tid; i < nE; i += 512) {
        int s = ei[e0 + i];
        int d = ei[N_EDGES + e0 + i];
        int b = d >> 8;
        int p = atomicAdd(&cur[b], 1);
        stage[p] = ((d & 255) << 17) | s;
    }
    __syncthreads();
    // coalesced run copy-out; bucket of position i via binary search in lofs
    for (int i = tid; i < nE; i += 512) {
        int pv = stage[i];
        int lo = 0, hi = NBK;   // invariant: lofs[lo] <= i < lofs[hi]
        while (hi - lo > 1) {
            int mid = (lo + hi) >> 1;
            if (lofs[mid] <= i) lo = mid; else hi = mid;
        }
        tmp[gbase[lo] + (i - lofs[lo])] = pv;
    }
}

// ---------------- CSR finalize: per-bucket node sort ----------------
__global__ __launch_bounds__(256) void csr_finalize_kernel(
    const int* __restrict__ bstart, const int* __restrict__ tmp,
    int* __restrict__ srcs, int* __restrict__ offsets) {
    __shared__ int cnt[BSZ];
    __shared__ int ofs[BSZ];
    __shared__ int cur[BSZ];
    int b = blockIdx.x, tid = threadIdx.x;
    int beg = bstart[b], end = bstart[b + 1];
    cnt[tid] = 0;
    __syncthreads();
    for (int i = beg + tid; i < end; i += 256)
        atomicAdd(&cnt[tmp[i] >> 17], 1);
    __syncthreads();
    int v = cnt[tid];
    ofs[tid] = v;
    __syncthreads();
    for (int off = 1; off < 256; off <<= 1) {
        int t = (tid >= off) ? ofs[tid - off] : 0;
        __syncthreads();
        ofs[tid] += t;
        __syncthreads();
    }
    int ex = ofs[tid] - v;
    cur[tid] = ex;
    int n = b * BSZ + tid;
    if (n < N_NODES) {
        offsets[n] = beg + ex;
        if (n == N_NODES - 1) offsets[N_NODES] = beg + ex + v;
    }
    __syncthreads();
    for (int i = beg + tid; i < end; i += 256) {
        int pv = tmp[i];
        int p = atomicAdd(&cur[pv >> 17], 1);
        srcs[beg + p] = pv & 0x1FFFF;
    }
}

// ---------------- gather: agg[n] = sum_{e in in(n)} h[src[e]] ----------------
// one wave per node (100K waves -> latency hidden by TLP); lane j owns
// feature j; 8 independent load chains (R6: 43.7 -> ~34.5us vs 4 chains).
__global__ __launch_bounds__(256) void gather_kernel(
    const int* __restrict__ offsets, const int* __restrict__ srcs,
    const float* __restrict__ h, float* __restrict__ agg) {
    int w = threadIdx.x >> 6, j = threadIdx.x & 63;
    int n = blockIdx.x * 4 + w;
    if (n >= N_NODES) return;
    int beg = offsets[n], end = offsets[n + 1];
    float acc0 = 0.f, acc1 = 0.f, acc2 = 0.f, acc3 = 0.f;
    float acc4 = 0.f, acc5 = 0.f, acc6 = 0.f, acc7 = 0.f;
    for (int c = beg; c < end; c += 64) {
        int myS = (c + j < end) ? srcs[c + j] : 0;
        int m = min(64, end - c);
        int i = 0;
        for (; i + 7 < m; i += 8) {
            int s0 = __shfl(myS, i);
            int s1 = __shfl(myS, i + 1);
            int s2 = __shfl(myS, i + 2);
            int s3 = __shfl(myS, i + 3);
            int s4 = __shfl(myS, i + 4);
            int s5 = __shfl(myS, i + 5);
            int s6 = __shfl(myS, i + 6);
            int s7 = __shfl(myS, i + 7);
            acc0 += h[(size_t)s0 * HID + j];
            acc1 += h[(size_t)s1 * HID + j];
            acc2 += h[(size_t)s2 * HID + j];
            acc3 += h[(size_t)s3 * HID + j];
            acc4 += h[(size_t)s4 * HID + j];
            acc5 += h[(size_t)s5 * HID + j];
            acc6 += h[(size_t)s6 * HID + j];
            acc7 += h[(size_t)s7 * HID + j];
        }
        for (; i + 3 < m; i += 4) {
            int s0 = __shfl(myS, i);
            int s1 = __shfl(myS, i + 1);
            int s2 = __shfl(myS, i + 2);
            int s3 = __shfl(myS, i + 3);
            acc0 += h[(size_t)s0 * HID + j];
            acc1 += h[(size_t)s1 * HID + j];
            acc2 += h[(size_t)s2 * HID + j];
            acc3 += h[(size_t)s3 * HID + j];
        }
        for (; i < m; i++) acc0 += h[(size_t)__shfl(myS, i) * HID + j];
    }
    agg[(size_t)n * HID + j] =
        (acc0 + acc1) + (acc2 + acc3) + ((acc4 + acc5) + (acc6 + acc7));
}

// ---------------- fused GIN MLP ----------------
// 512 threads, 64-node tile, 2x4 register micro-tile (8 accs), 49 KB LDS
// -> 3 blocks/CU (~24 waves/CU). R6 lesson: occupancy beats per-thread
// arithmetic intensity for this barrier-phased kernel.
__global__ __launch_bounds__(512) void mlp_kernel(
    float* __restrict__ h, const float* __restrict__ agg,
    const float* __restrict__ w1, const float* __restrict__ b1,
    const float* __restrict__ w2, const float* __restrict__ b2) {
    __shared__ float w1s[HID * HID];   // 16 KB
    __shared__ float w2s[HID * HID];   // 16 KB
    __shared__ float ms[64 * MPAD];    // 17 KB, reused for t
    int tid = threadIdx.x;
    int row0 = blockIdx.x * 64;
    for (int i = tid; i < HID * HID / 4; i += 512) {
        ((float4*)w1s)[i] = ((const float4*)w1)[i];
        ((float4*)w2s)[i] = ((const float4*)w2)[i];
    }
#pragma unroll
    for (int i = 0; i < 2; i++) {
        int f = tid + i * 512;
        int r = f >> 4, c4 = f & 15;
        int n = row0 + r;
        float4 mv = make_float4(0.f, 0.f, 0.f, 0.f);
        if (n < N_NODES) {
            float4 h4 = ((const float4*)(h + (size_t)n * HID))[c4];
            float4 a4 = ((const float4*)(agg + (size_t)n * HID))[c4];
            mv = make_float4(h4.x + a4.x, h4.y + a4.y, h4.z + a4.z, h4.w + a4.w);
        }
        *(float4*)&ms[r * MPAD + c4 * 4] = mv;
    }
    __syncthreads();

    int ty = tid >> 4, tx = tid & 15;   // ty 0..31, tx 0..15
    int r0 = ty * 2, c0 = tx * 4;

    float4 a0, a1;
#define GEMM_LDS(WS)                                                          \
    do {                                                                      \
        a0 = make_float4(0.f, 0.f, 0.f, 0.f); a1 = a0;                        \
        _Pragma("unroll 4")                                                   \
        for (int k0 = 0; k0 < HID; k0 += 4) {                                 \
            float4 m0 = *(const float4*)&ms[(r0 + 0) * MPAD + k0];            \
            float4 m1 = *(const float4*)&ms[(r0 + 1) * MPAD + k0];            \
            float4 w0 = *(const float4*)&WS[(k0 + 0) * HID + c0];             \
            float4 w1v = *(const float4*)&WS[(k0 + 1) * HID + c0];            \
            float4 w2v = *(const float4*)&WS[(k0 + 2) * HID + c0];            \
            float4 w3v = *(const float4*)&WS[(k0 + 3) * HID + c0];            \
            a0.x += m0.x * w0.x + m0.y * w1v.x + m0.z * w2v.x + m0.w * w3v.x; \
            a0.y += m0.x * w0.y + m0.y * w1v.y + m0.z * w2v.y + m0.w * w3v.y; \
            a0.z += m0.x * w0.z + m0.y * w1v.z + m0.z * w2v.z + m0.w * w3v.z; \
            a0.w += m0.x * w0.w + m0.y * w1v.w + m0.z * w2v.w + m0.w * w3v.w; \
            a1.x += m1.x * w0.x + m1.y * w1v.x + m1.z * w2v.x + m1.w * w3v.x; \
            a1.y += m1.x * w0.y + m1.y * w1v.y + m1.z * w2v.y + m1.w * w3v.y; \
            a1.z += m1.x * w0.z + m1.y * w1v.z + m1.z * w2v.z + m1.w * w3v.z; \
            a1.w += m1.x * w0.w + m1.y * w1v.w + m1.z * w2v.w + m1.w * w3v.w; \
        }                                                                     \
    } while (0)

    GEMM_LDS(w1s);  // GEMM1

    float4 bv1 = *(const float4*)&b1[c0];
    float4 t0 = make_float4(fmaxf(a0.x + bv1.x, 0.f), fmaxf(a0.y + bv1.y, 0.f),
                            fmaxf(a0.z + bv1.z, 0.f), fmaxf(a0.w + bv1.w, 0.f));
    float4 t1 = make_float4(fmaxf(a1.x + bv1.x, 0.f), fmaxf(a1.y + bv1.y, 0.f),
                            fmaxf(a1.z + bv1.z, 0.f), fmaxf(a1.w + bv1.w, 0.f));

    __syncthreads();  // all GEMM1 reads of ms complete
    *(float4*)&ms[(r0 + 0) * MPAD + c0] = t0;
    *(float4*)&ms[(r0 + 1) * MPAD + c0] = t1;
    __syncthreads();

    GEMM_LDS(w2s);  // GEMM2

    float4 bv2 = *(const float4*)&b2[c0];
#pragma unroll
    for (int i = 0; i < 2; i++) {
        int n = row0 + r0 + i;
        if (n < N_NODES) {
            float4 av = (i == 0) ? a0 : a1;
            float4 hold = *(const float4*)(h + (size_t)n * HID + c0);
            float4 o;
            o.x = fmaxf(av.x + bv2.x, 0.f) + hold.x;
            o.y = fmaxf(av.y + bv2.y, 0.f) + hold.y;
            o.z = fmaxf(av.z + bv2.z, 0.f) + hold.z;
            o.w = fmaxf(av.w + bv2.w, 0.f) + hold.w;
            *(float4*)(h + (size_t)n * HID + c0) = o;
        }
    }
#undef GEMM_LDS
}

// ---------------- global add pool ----------------
__global__ __launch_bounds__(256) void pool_kernel(
    const float* __restrict__ h, const int* __restrict__ batch,
    float* __restrict__ pooled) {
    int tid = threadIdx.x;
    int w = tid >> 6, j = tid & 63;
    int n0 = blockIdx.x * 256 + w * 64;
    if (n0 >= N_NODES) return;
    int nend = min(n0 + 64, N_NODES);
    float acc = 0.f;
    int cur = batch[n0];
    for (int n = n0; n < nend; n++) {
        int b = batch[n];
        if (b != cur) {
            atomicAdd(&pooled[cur * HID + j], acc);
            acc = 0.f;
            cur = b;
        }
        acc += h[(size_t)n * HID + j];
    }
    atomicAdd(&pooled[cur * HID + j], acc);
}

// ---------------- final FC ----------------
__global__ __launch_bounds__(256) void final_kernel(
    const float* __restrict__ pooled, const float* __restrict__ w_fc,
    const float* __restrict__ b_fc, float* __restrict__ out) {
    int gid = blockIdx.x * 256 + threadIdx.x;
    if (gid >= N_GRAPHS * LAT) return;
    int g = gid >> 5, j = gid & 31;
    float acc = b_fc[j];
#pragma unroll
    for (int k = 0; k < HID; k++)
        acc += pooled[g * HID + k] * w_fc[k * LAT + j];
    out[gid] = acc;
}

extern "C" void kernel_launch(void* const* d_in, const int* in_sizes, int n_in,
                              void* d_out, int out_size, void* d_ws,
                              size_t ws_size, hipStream_t stream) {
    const float* x     = (const float*)d_in[0];
    const int*   ei    = (const int*)d_in[1];
    const int*   batch = (const int*)d_in[2];
    const float* w_in  = (const float*)d_in[3];
    const float* b_in  = (const float*)d_in[4];
    const float* w1    = (const float*)d_in[5];
    const float* b1    = (const float*)d_in[6];
    const float* w2    = (const float*)d_in[7];
    const float* b2    = (const float*)d_in[8];
    const float* w_fc  = (const float*)d_in[9];
    const float* b_fc  = (const float*)d_in[10];
    float* out = (float*)d_out;

    // persistent: h | agg | pooled | offsets | srcs   (~55.6 MB)
    float* h       = (float*)d_ws;
    float* agg     = h + (size_t)N_NODES * HID;
    float* pooled  = agg + (size_t)N_NODES * HID;
    int*   offsets = (int*)(pooled + N_GRAPHS * HID);   // N_NODES+1
    int*   srcs    = offsets + (N_NODES + 2);           // N_EDGES
    // build-time arrays overlaid into agg's region (dead before first gather)
    int* tmp     = (int*)agg;            // N_EDGES packed bucket-major edges
    int* bhist   = tmp + N_EDGES;        // NBK
    int* bstart  = bhist + NBK;          // NBK + 1
    int* bcursor = bstart + (NBK + 1);   // NBK

    proj_kernel<<<(N_NODES + 3) / 4, 256, 0, stream>>>(x, w_in, b_in, h);

    // coalesced CSR build (once; edges constant across layers)
    hipMemsetAsync(bhist, 0, NBK * sizeof(int), stream);
    bhist_kernel<<<(N_EDGES + 4095) / 4096, 256, 0, stream>>>(ei, bhist);
    bscan_kernel<<<1, 512, 0, stream>>>(bhist, bstart, bcursor);
    binsort_kernel<<<NBIN_BLOCKS, 512, 0, stream>>>(ei, bcursor, tmp);
    csr_finalize_kernel<<<NBK, 256, 0, stream>>>(bstart, tmp, srcs, offsets);

    for (int i = 0; i < N_LAYERS; i++) {
        gather_kernel<<<(N_NODES + 3) / 4, 256, 0, stream>>>(offsets, srcs, h, agg);
        mlp_kernel<<<(N_NODES + 63) / 64, 512, 0, stream>>>(
            h, agg, w1 + (size_t)i * HID * HID, b1 + (size_t)i * HID,
            w2 + (size_t)i * HID * HID, b2 + (size_t)i * HID);
    }

    hipMemsetAsync(pooled, 0, N_GRAPHS * HID * sizeof(float), stream);
    pool_kernel<<<(N_NODES + 255) / 256, 256, 0, stream>>>(h, batch, pooled);
    final_kernel<<<(N_GRAPHS * LAT + 255) / 256, 256, 0, stream>>>(
        pooled, w_fc, b_fc, out);
}

// Round 9
// 399.711 us; speedup vs baseline: 1.1764x; 1.0231x over previous
//
#include <hip/hip_runtime.h>

#define N_NODES 100000
#define N_EDGES 1000000
#define N_GRAPHS 128
#define IN_DIM 32
#define HID 64
#define LAT 32
#define N_LAYERS 3

#define MPAD 68  // padded LDS row stride (floats), 16B-aligned rows

// ---- dst-bucket edge build (coalesced CSR construction) ----
#define BSZ 256                                  // nodes per bucket
#define NBK ((N_NODES + BSZ - 1) / BSZ)          // 391 buckets
#define EPB 4096                                 // edges per binsort block
                                                 // (R3: 16384 -> 62 blocks, 4.7% occ, 46us;
                                                 //  4096 -> 245 blocks ~1/CU, latency hidden)
#define NBIN_BLOCKS ((N_EDGES + EPB - 1) / EPB)  // 245

// R5 lesson: do NOT fuse gather into the MLP kernel (lockstep phases serialize
// at half the memory parallelism). R6 lesson: mlp IS LDS-issue-bound (VALUBusy
// 33% == 6 ds_read_b128 per 32 CU-VALU-cyc), but fixing it must NOT cost
// blocks/CU: 4x4 tile at 128 nodes -> 67KB LDS -> 2 blocks/CU -> 16.7% occ,
// 36->50us. R8: 4x4 tile at 64 nodes / 256 threads keeps 49KB (3 blocks/CU).

// ---------------- input projection: h = x @ w_in + b_in ----------------
__global__ __launch_bounds__(256) void proj_kernel(
    const float* __restrict__ x, const float* __restrict__ w_in,
    const float* __restrict__ b_in, float* __restrict__ h) {
    __shared__ float ws[IN_DIM * HID];   // 8 KB
    __shared__ float xs[4 * IN_DIM];
    int tid = threadIdx.x;
    for (int i = tid; i < IN_DIM * HID / 4; i += 256)
        ((float4*)ws)[i] = ((const float4*)w_in)[i];
    if (tid < 32) {
        int r = tid >> 3, c4 = tid & 7;
        int nn = blockIdx.x * 4 + r;
        float4 v = make_float4(0.f, 0.f, 0.f, 0.f);
        if (nn < N_NODES) v = ((const float4*)(x + (size_t)nn * IN_DIM))[c4];
        ((float4*)xs)[tid] = v;
    }
    __syncthreads();
    int w = tid >> 6, j = tid & 63;
    int n = blockIdx.x * 4 + w;
    if (n >= N_NODES) return;
    float acc = b_in[j];
#pragma unroll
    for (int k = 0; k < IN_DIM; k += 4) {
        float4 xv = *(const float4*)&xs[w * IN_DIM + k];
        acc += xv.x * ws[(k + 0) * HID + j];
        acc += xv.y * ws[(k + 1) * HID + j];
        acc += xv.z * ws[(k + 2) * HID + j];
        acc += xv.w * ws[(k + 3) * HID + j];
    }
    h[(size_t)n * HID + j] = acc;
}

// ---------------- bucket histogram (LDS-aggregated) ----------------
__global__ __launch_bounds__(256) void bhist_kernel(const int* __restrict__ ei,
                                                    int* __restrict__ bhist) {
    __shared__ int hs[NBK];
    for (int i = threadIdx.x; i < NBK; i += 256) hs[i] = 0;
    __syncthreads();
    int e = blockIdx.x * (256 * 16) + threadIdx.x;
#pragma unroll
    for (int k = 0; k < 16; k++, e += 256)
        if (e < N_EDGES) atomicAdd(&hs[ei[N_EDGES + e] >> 8], 1);
    __syncthreads();
    for (int i = threadIdx.x; i < NBK; i += 256) {
        int c = hs[i];
        if (c) atomicAdd(&bhist[i], c);
    }
}

// ---------------- bucket scan: bstart (exclusive) + cursor init ----------------
__global__ __launch_bounds__(512) void bscan_kernel(const int* __restrict__ bhist,
                                                    int* __restrict__ bstart,
                                                    int* __restrict__ bcursor) {
    __shared__ int sc[512];
    int tid = threadIdx.x;
    int v = (tid < NBK) ? bhist[tid] : 0;
    sc[tid] = v;
    __syncthreads();
    for (int off = 1; off < 512; off <<= 1) {
        int t = (tid >= off) ? sc[tid - off] : 0;
        __syncthreads();
        sc[tid] += t;
        __syncthreads();
    }
    if (tid < NBK) {
        int ex = sc[tid] - v;
        bstart[tid] = ex;
        bcursor[tid] = ex;
    }
    if (tid == 0) bstart[NBK] = N_EDGES;
}

// ---------------- binsort: scatter edges into bucket-major order ----------------
// Packed entry: (dst & 255) << 17 | src  (src < 2^17)
__global__ __launch_bounds__(512) void binsort_kernel(const int* __restrict__ ei,
                                                      int* __restrict__ bcursor,
                                                      int* __restrict__ tmp) {
    __shared__ int hist[NBK];
    __shared__ int lofs[NBK + 1];
    __shared__ int cur[NBK];
    __shared__ int gbase[NBK];
    __shared__ int sc[512];
    __shared__ int stage[EPB];   // 16 KB
    int tid = threadIdx.x;
    int e0 = blockIdx.x * EPB;
    int nE = min(EPB, N_EDGES - e0);
    for (int i = tid; i < NBK; i += 512) hist[i] = 0;
    __syncthreads();
    // local count
    for (int i = tid; i < nE; i += 512)
        atomicAdd(&hist[ei[N_EDGES + e0 + i] >> 8], 1);
    __syncthreads();
    // local scan (Hillis-Steele over 512)
    int v = (tid < NBK) ? hist[tid] : 0;
    sc[tid] = v;
    __syncthreads();
    for (int off = 1; off < 512; off <<= 1) {
        int t = (tid >= off) ? sc[tid - off] : 0;
        __syncthreads();
        sc[tid] += t;
        __syncthreads();
    }
    if (tid < NBK) {
        int ex = sc[tid] - v;
        lofs[tid] = ex;
        cur[tid] = ex;
        gbase[tid] = atomicAdd(&bcursor[tid], v);  // one reserve per bucket
    }
    if (tid == 0) lofs[NBK] = nE;
    __syncthreads();
    // local place (group by bucket in LDS; edges L2-hot from count pass)
    for (int i = tid; i < nE; i += 512) {
        int s = ei[e0 + i];
        int d = ei[N_EDGES + e0 + i];
        int b = d >> 8;
        int p = atomicAdd(&cur[b], 1);
        stage[p] = ((d & 255) << 17) | s;
    }
    __syncthreads();
    // coalesced run copy-out; bucket of position i via binary search in lofs
    for (int i = tid; i < nE; i += 512) {
        int pv = stage[i];
        int lo = 0, hi = NBK;   // invariant: lofs[lo] <= i < lofs[hi]
        while (hi - lo > 1) {
            int mid = (lo + hi) >> 1;
            if (lofs[mid] <= i) lo = mid; else hi = mid;
        }
        tmp[gbase[lo] + (i - lofs[lo])] = pv;
    }
}

// ---------------- CSR finalize: per-bucket node sort ----------------
__global__ __launch_bounds__(256) void csr_finalize_kernel(
    const int* __restrict__ bstart, const int* __restrict__ tmp,
    int* __restrict__ srcs, int* __restrict__ offsets) {
    __shared__ int cnt[BSZ];
    __shared__ int ofs[BSZ];
    __shared__ int cur[BSZ];
    int b = blockIdx.x, tid = threadIdx.x;
    int beg = bstart[b], end = bstart[b + 1];
    cnt[tid] = 0;
    __syncthreads();
    for (int i = beg + tid; i < end; i += 256)
        atomicAdd(&cnt[tmp[i] >> 17], 1);
    __syncthreads();
    int v = cnt[tid];
    ofs[tid] = v;
    __syncthreads();
    for (int off = 1; off < 256; off <<= 1) {
        int t = (tid >= off) ? ofs[tid - off] : 0;
        __syncthreads();
        ofs[tid] += t;
        __syncthreads();
    }
    int ex = ofs[tid] - v;
    cur[tid] = ex;
    int n = b * BSZ + tid;
    if (n < N_NODES) {
        offsets[n] = beg + ex;
        if (n == N_NODES - 1) offsets[N_NODES] = beg + ex + v;
    }
    __syncthreads();
    for (int i = beg + tid; i < end; i += 256) {
        int pv = tmp[i];
        int p = atomicAdd(&cur[pv >> 17], 1);
        srcs[beg + p] = pv & 0x1FFFF;
    }
}

// ---------------- gather: agg[n] = sum_{e in in(n)} h[src[e]] ----------------
// one wave per node (100K waves -> latency hidden by TLP); lane j owns
// feature j; 8 independent load chains (R6: 43.7 -> ~34.5us vs 4 chains).
__global__ __launch_bounds__(256) void gather_kernel(
    const int* __restrict__ offsets, const int* __restrict__ srcs,
    const float* __restrict__ h, float* __restrict__ agg) {
    int w = threadIdx.x >> 6, j = threadIdx.x & 63;
    int n = blockIdx.x * 4 + w;
    if (n >= N_NODES) return;
    int beg = offsets[n], end = offsets[n + 1];
    float acc0 = 0.f, acc1 = 0.f, acc2 = 0.f, acc3 = 0.f;
    float acc4 = 0.f, acc5 = 0.f, acc6 = 0.f, acc7 = 0.f;
    for (int c = beg; c < end; c += 64) {
        int myS = (c + j < end) ? srcs[c + j] : 0;
        int m = min(64, end - c);
        int i = 0;
        for (; i + 7 < m; i += 8) {
            int s0 = __shfl(myS, i);
            int s1 = __shfl(myS, i + 1);
            int s2 = __shfl(myS, i + 2);
            int s3 = __shfl(myS, i + 3);
            int s4 = __shfl(myS, i + 4);
            int s5 = __shfl(myS, i + 5);
            int s6 = __shfl(myS, i + 6);
            int s7 = __shfl(myS, i + 7);
            acc0 += h[(size_t)s0 * HID + j];
            acc1 += h[(size_t)s1 * HID + j];
            acc2 += h[(size_t)s2 * HID + j];
            acc3 += h[(size_t)s3 * HID + j];
            acc4 += h[(size_t)s4 * HID + j];
            acc5 += h[(size_t)s5 * HID + j];
            acc6 += h[(size_t)s6 * HID + j];
            acc7 += h[(size_t)s7 * HID + j];
        }
        for (; i + 3 < m; i += 4) {
            int s0 = __shfl(myS, i);
            int s1 = __shfl(myS, i + 1);
            int s2 = __shfl(myS, i + 2);
            int s3 = __shfl(myS, i + 3);
            acc0 += h[(size_t)s0 * HID + j];
            acc1 += h[(size_t)s1 * HID + j];
            acc2 += h[(size_t)s2 * HID + j];
            acc3 += h[(size_t)s3 * HID + j];
        }
        for (; i < m; i++) acc0 += h[(size_t)__shfl(myS, i) * HID + j];
    }
    agg[(size_t)n * HID + j] =
        (acc0 + acc1) + (acc2 + acc3) + ((acc4 + acc5) + (acc6 + acc7));
}

// ---------------- fused GIN MLP ----------------
// 256 threads, 64-node tile, 4x4 register micro-tile (16 accs), 49 KB LDS
// -> 3 blocks/CU (12 waves/CU). vs R7's 2x4/512thr: halves the waves but
// 1.5x better ds_read_b128-per-FLOP ratio (8 reads / 128 VALU-cyc vs
// 6 / 64) — mlp is LDS-issue-bound (VALUBusy 33% == the 6:32 ratio).
__global__ __launch_bounds__(256) void mlp_kernel(
    float* __restrict__ h, const float* __restrict__ agg,
    const float* __restrict__ w1, const float* __restrict__ b1,
    const float* __restrict__ w2, const float* __restrict__ b2) {
    __shared__ float w1s[HID * HID];   // 16 KB
    __shared__ float w2s[HID * HID];   // 16 KB
    __shared__ float ms[64 * MPAD];    // 17 KB, reused for t
    int tid = threadIdx.x;
    int row0 = blockIdx.x * 64;
    for (int i = tid; i < HID * HID / 4; i += 256) {
        ((float4*)w1s)[i] = ((const float4*)w1)[i];
        ((float4*)w2s)[i] = ((const float4*)w2)[i];
    }
#pragma unroll
    for (int i = 0; i < 4; i++) {
        int f = tid + i * 256;
        int r = f >> 4, c4 = f & 15;
        int n = row0 + r;
        float4 mv = make_float4(0.f, 0.f, 0.f, 0.f);
        if (n < N_NODES) {
            float4 h4 = ((const float4*)(h + (size_t)n * HID))[c4];
            float4 a4 = ((const float4*)(agg + (size_t)n * HID))[c4];
            mv = make_float4(h4.x + a4.x, h4.y + a4.y, h4.z + a4.z, h4.w + a4.w);
        }
        *(float4*)&ms[r * MPAD + c4 * 4] = mv;
    }
    __syncthreads();

    int ty = tid >> 4, tx = tid & 15;   // ty 0..15, tx 0..15
    int r0 = ty * 4, c0 = tx * 4;

    float4 a0, a1, a2, a3;
#define GEMM_LDS(WS)                                                          \
    do {                                                                      \
        a0 = make_float4(0.f, 0.f, 0.f, 0.f); a1 = a0; a2 = a0; a3 = a0;      \
        _Pragma("unroll 4")                                                   \
        for (int k0 = 0; k0 < HID; k0 += 4) {                                 \
            float4 m0 = *(const float4*)&ms[(r0 + 0) * MPAD + k0];            \
            float4 m1 = *(const float4*)&ms[(r0 + 1) * MPAD + k0];            \
            float4 m2 = *(const float4*)&ms[(r0 + 2) * MPAD + k0];            \
            float4 m3 = *(const float4*)&ms[(r0 + 3) * MPAD + k0];            \
            float4 w0 = *(const float4*)&WS[(k0 + 0) * HID + c0];             \
            float4 w1v = *(const float4*)&WS[(k0 + 1) * HID + c0];            \
            float4 w2v = *(const float4*)&WS[(k0 + 2) * HID + c0];            \
            float4 w3v = *(const float4*)&WS[(k0 + 3) * HID + c0];            \
            a0.x += m0.x * w0.x + m0.y * w1v.x + m0.z * w2v.x + m0.w * w3v.x; \
            a0.y += m0.x * w0.y + m0.y * w1v.y + m0.z * w2v.y + m0.w * w3v.y; \
            a0.z += m0.x * w0.z + m0.y * w1v.z + m0.z * w2v.z + m0.w * w3v.z; \
            a0.w += m0.x * w0.w + m0.y * w1v.w + m0.z * w2v.w + m0.w * w3v.w; \
            a1.x += m1.x * w0.x + m1.y * w1v.x + m1.z * w2v.x + m1.w * w3v.x; \
            a1.y += m1.x * w0.y + m1.y * w1v.y + m1.z * w2v.y + m1.w * w3v.y; \
            a1.z += m1.x * w0.z + m1.y * w1v.z + m1.z * w2v.z + m1.w * w3v.z; \
            a1.w += m1.x * w0.w + m1.y * w1v.w + m1.z * w2v.w + m1.w * w3v.w; \
            a2.x += m2.x * w0.x + m2.y * w1v.x + m2.z * w2v.x + m2.w * w3v.x; \
            a2.y += m2.x * w0.y + m2.y * w1v.y + m2.z * w2v.y + m2.w * w3v.y; \
            a2.z += m2.x * w0.z + m2.y * w1v.z + m2.z * w2v.z + m2.w * w3v.z; \
            a2.w += m2.x * w0.w + m2.y * w1v.w + m2.z * w2v.w + m2.w * w3v.w; \
            a3.x += m3.x * w0.x + m3.y * w1v.x + m3.z * w2v.x + m3.w * w3v.x; \
            a3.y += m3.x * w0.y + m3.y * w1v.y + m3.z * w2v.y + m3.w * w3v.y; \
            a3.z += m3.x * w0.z + m3.y * w1v.z + m3.z * w2v.z + m3.w * w3v.z; \
            a3.w += m3.x * w0.w + m3.y * w1v.w + m3.z * w2v.w + m3.w * w3v.w; \
        }                                                                     \
    } while (0)

    GEMM_LDS(w1s);  // GEMM1

    float4 bv1 = *(const float4*)&b1[c0];
    float4 t0 = make_float4(fmaxf(a0.x + bv1.x, 0.f), fmaxf(a0.y + bv1.y, 0.f),
                            fmaxf(a0.z + bv1.z, 0.f), fmaxf(a0.w + bv1.w, 0.f));
    float4 t1 = make_float4(fmaxf(a1.x + bv1.x, 0.f), fmaxf(a1.y + bv1.y, 0.f),
                            fmaxf(a1.z + bv1.z, 0.f), fmaxf(a1.w + bv1.w, 0.f));
    float4 t2 = make_float4(fmaxf(a2.x + bv1.x, 0.f), fmaxf(a2.y + bv1.y, 0.f),
                            fmaxf(a2.z + bv1.z, 0.f), fmaxf(a2.w + bv1.w, 0.f));
    float4 t3 = make_float4(fmaxf(a3.x + bv1.x, 0.f), fmaxf(a3.y + bv1.y, 0.f),
                            fmaxf(a3.z + bv1.z, 0.f), fmaxf(a3.w + bv1.w, 0.f));

    __syncthreads();  // all GEMM1 reads of ms complete
    *(float4*)&ms[(r0 + 0) * MPAD + c0] = t0;
    *(float4*)&ms[(r0 + 1) * MPAD + c0] = t1;
    *(float4*)&ms[(r0 + 2) * MPAD + c0] = t2;
    *(float4*)&ms[(r0 + 3) * MPAD + c0] = t3;
    __syncthreads();

    GEMM_LDS(w2s);  // GEMM2

    float4 bv2 = *(const float4*)&b2[c0];
#pragma unroll
    for (int i = 0; i < 4; i++) {
        int n = row0 + r0 + i;
        if (n < N_NODES) {
            float4 av = (i == 0) ? a0 : (i == 1) ? a1 : (i == 2) ? a2 : a3;
            float4 hold = *(const float4*)(h + (size_t)n * HID + c0);
            float4 o;
            o.x = fmaxf(av.x + bv2.x, 0.f) + hold.x;
            o.y = fmaxf(av.y + bv2.y, 0.f) + hold.y;
            o.z = fmaxf(av.z + bv2.z, 0.f) + hold.z;
            o.w = fmaxf(av.w + bv2.w, 0.f) + hold.w;
            *(float4*)(h + (size_t)n * HID + c0) = o;
        }
    }
#undef GEMM_LDS
}

// ---------------- global add pool ----------------
__global__ __launch_bounds__(256) void pool_kernel(
    const float* __restrict__ h, const int* __restrict__ batch,
    float* __restrict__ pooled) {
    int tid = threadIdx.x;
    int w = tid >> 6, j = tid & 63;
    int n0 = blockIdx.x * 256 + w * 64;
    if (n0 >= N_NODES) return;
    int nend = min(n0 + 64, N_NODES);
    float acc = 0.f;
    int cur = batch[n0];
    for (int n = n0; n < nend; n++) {
        int b = batch[n];
        if (b != cur) {
            atomicAdd(&pooled[cur * HID + j], acc);
            acc = 0.f;
            cur = b;
        }
        acc += h[(size_t)n * HID + j];
    }
    atomicAdd(&pooled[cur * HID + j], acc);
}

// ---------------- final FC ----------------
__global__ __launch_bounds__(256) void final_kernel(
    const float* __restrict__ pooled, const float* __restrict__ w_fc,
    const float* __restrict__ b_fc, float* __restrict__ out) {
    int gid = blockIdx.x * 256 + threadIdx.x;
    if (gid >= N_GRAPHS * LAT) return;
    int g = gid >> 5, j = gid & 31;
    float acc = b_fc[j];
#pragma unroll
    for (int k = 0; k < HID; k++)
        acc += pooled[g * HID + k] * w_fc[k * LAT + j];
    out[gid] = acc;
}

extern "C" void kernel_launch(void* const* d_in, const int* in_sizes, int n_in,
                              void* d_out, int out_size, void* d_ws,
                              size_t ws_size, hipStream_t stream) {
    const float* x     = (const float*)d_in[0];
    const int*   ei    = (const int*)d_in[1];
    const int*   batch = (const int*)d_in[2];
    const float* w_in  = (const float*)d_in[3];
    const float* b_in  = (const float*)d_in[4];
    const float* w1    = (const float*)d_in[5];
    const float* b1    = (const float*)d_in[6];
    const float* w2    = (const float*)d_in[7];
    const float* b2    = (const float*)d_in[8];
    const float* w_fc  = (const float*)d_in[9];
    const float* b_fc  = (const float*)d_in[10];
    float* out = (float*)d_out;

    // persistent: h | agg | pooled | offsets | srcs   (~55.6 MB)
    float* h       = (float*)d_ws;
    float* agg     = h + (size_t)N_NODES * HID;
    float* pooled  = agg + (size_t)N_NODES * HID;
    int*   offsets = (int*)(pooled + N_GRAPHS * HID);   // N_NODES+1
    int*   srcs    = offsets + (N_NODES + 2);           // N_EDGES
    // build-time arrays overlaid into agg's region (dead before first gather)
    int* tmp     = (int*)agg;            // N_EDGES packed bucket-major edges
    int* bhist   = tmp + N_EDGES;        // NBK
    int* bstart  = bhist + NBK;          // NBK + 1
    int* bcursor = bstart + (NBK + 1);   // NBK

    proj_kernel<<<(N_NODES + 3) / 4, 256, 0, stream>>>(x, w_in, b_in, h);

    // coalesced CSR build (once; edges constant across layers)
    hipMemsetAsync(bhist, 0, NBK * sizeof(int), stream);
    bhist_kernel<<<(N_EDGES + 4095) / 4096, 256, 0, stream>>>(ei, bhist);
    bscan_kernel<<<1, 512, 0, stream>>>(bhist, bstart, bcursor);
    binsort_kernel<<<NBIN_BLOCKS, 512, 0, stream>>>(ei, bcursor, tmp);
    csr_finalize_kernel<<<NBK, 256, 0, stream>>>(bstart, tmp, srcs, offsets);

    for (int i = 0; i < N_LAYERS; i++) {
        gather_kernel<<<(N_NODES + 3) / 4, 256, 0, stream>>>(offsets, srcs, h, agg);
        mlp_kernel<<<(N_NODES + 63) / 64, 256, 0, stream>>>(
            h, agg, w1 + (size_t)i * HID * HID, b1 + (size_t)i * HID,
            w2 + (size_t)i * HID * HID, b2 + (size_t)i * HID);
    }

    hipMemsetAsync(pooled, 0, N_GRAPHS * HID * sizeof(float), stream);
    pool_kernel<<<(N_NODES + 255) / 256, 256, 0, stream>>>(h, batch, pooled);
    final_kernel<<<(N_GRAPHS * LAT + 255) / 256, 256, 0, stream>>>(
        pooled, w_fc, b_fc, out);
}

// Round 10
// 396.428 us; speedup vs baseline: 1.1862x; 1.0083x over previous
//
#include <hip/hip_runtime.h>

#define N_NODES 100000
#define N_EDGES 1000000
#define N_GRAPHS 128
#define IN_DIM 32
#define HID 64
#define LAT 32
#define N_LAYERS 3

#define MPAD 68  // padded LDS row stride (floats), 16B-aligned rows

// ---- dst-bucket edge build (coalesced CSR construction) ----
#define BSZ 256                                  // nodes per bucket
#define NBK ((N_NODES + BSZ - 1) / BSZ)          // 391 buckets
#define EPB 4096                                 // edges per binsort block
#define NBIN_BLOCKS ((N_EDGES + EPB - 1) / EPB)  // 245

// R5: don't fuse gather+MLP (lockstep phases serialize at low occupancy).
// R6: mlp is LDS-issue-bound; fix ratio without losing blocks/CU.
// R9: 4x4 micro-tile @64 nodes/256thr = win (400us total).
// R10: gather is VMEM-issue-bound (28% VALU, 40% HBM, 65% occ) -> quad-row
// float4 gather: 4 edges per VMEM instruction instead of 1.

// ---------------- input projection: h = x @ w_in + b_in ----------------
__global__ __launch_bounds__(256) void proj_kernel(
    const float* __restrict__ x, const float* __restrict__ w_in,
    const float* __restrict__ b_in, float* __restrict__ h) {
    __shared__ float ws[IN_DIM * HID];   // 8 KB
    __shared__ float xs[4 * IN_DIM];
    int tid = threadIdx.x;
    for (int i = tid; i < IN_DIM * HID / 4; i += 256)
        ((float4*)ws)[i] = ((const float4*)w_in)[i];
    if (tid < 32) {
        int r = tid >> 3, c4 = tid & 7;
        int nn = blockIdx.x * 4 + r;
        float4 v = make_float4(0.f, 0.f, 0.f, 0.f);
        if (nn < N_NODES) v = ((const float4*)(x + (size_t)nn * IN_DIM))[c4];
        ((float4*)xs)[tid] = v;
    }
    __syncthreads();
    int w = tid >> 6, j = tid & 63;
    int n = blockIdx.x * 4 + w;
    if (n >= N_NODES) return;
    float acc = b_in[j];
#pragma unroll
    for (int k = 0; k < IN_DIM; k += 4) {
        float4 xv = *(const float4*)&xs[w * IN_DIM + k];
        acc += xv.x * ws[(k + 0) * HID + j];
        acc += xv.y * ws[(k + 1) * HID + j];
        acc += xv.z * ws[(k + 2) * HID + j];
        acc += xv.w * ws[(k + 3) * HID + j];
    }
    h[(size_t)n * HID + j] = acc;
}

// ---------------- bucket histogram (LDS-aggregated) ----------------
__global__ __launch_bounds__(256) void bhist_kernel(const int* __restrict__ ei,
                                                    int* __restrict__ bhist) {
    __shared__ int hs[NBK];
    for (int i = threadIdx.x; i < NBK; i += 256) hs[i] = 0;
    __syncthreads();
    int e = blockIdx.x * (256 * 16) + threadIdx.x;
#pragma unroll
    for (int k = 0; k < 16; k++, e += 256)
        if (e < N_EDGES) atomicAdd(&hs[ei[N_EDGES + e] >> 8], 1);
    __syncthreads();
    for (int i = threadIdx.x; i < NBK; i += 256) {
        int c = hs[i];
        if (c) atomicAdd(&bhist[i], c);
    }
}

// ---------------- bucket scan: bstart (exclusive) + cursor init ----------------
__global__ __launch_bounds__(512) void bscan_kernel(const int* __restrict__ bhist,
                                                    int* __restrict__ bstart,
                                                    int* __restrict__ bcursor) {
    __shared__ int sc[512];
    int tid = threadIdx.x;
    int v = (tid < NBK) ? bhist[tid] : 0;
    sc[tid] = v;
    __syncthreads();
    for (int off = 1; off < 512; off <<= 1) {
        int t = (tid >= off) ? sc[tid - off] : 0;
        __syncthreads();
        sc[tid] += t;
        __syncthreads();
    }
    if (tid < NBK) {
        int ex = sc[tid] - v;
        bstart[tid] = ex;
        bcursor[tid] = ex;
    }
    if (tid == 0) bstart[NBK] = N_EDGES;
}

// ---------------- binsort: scatter edges into bucket-major order ----------------
// Packed entry: (dst & 255) << 17 | src  (src < 2^17)
__global__ __launch_bounds__(512) void binsort_kernel(const int* __restrict__ ei,
                                                      int* __restrict__ bcursor,
                                                      int* __restrict__ tmp) {
    __shared__ int hist[NBK];
    __shared__ int lofs[NBK + 1];
    __shared__ int cur[NBK];
    __shared__ int gbase[NBK];
    __shared__ int sc[512];
    __shared__ int stage[EPB];   // 16 KB
    int tid = threadIdx.x;
    int e0 = blockIdx.x * EPB;
    int nE = min(EPB, N_EDGES - e0);
    for (int i = tid; i < NBK; i += 512) hist[i] = 0;
    __syncthreads();
    // local count
    for (int i = tid; i < nE; i += 512)
        atomicAdd(&hist[ei[N_EDGES + e0 + i] >> 8], 1);
    __syncthreads();
    // local scan (Hillis-Steele over 512)
    int v = (tid < NBK) ? hist[tid] : 0;
    sc[tid] = v;
    __syncthreads();
    for (int off = 1; off < 512; off <<= 1) {
        int t = (tid >= off) ? sc[tid - off] : 0;
        __syncthreads();
        sc[tid] += t;
        __syncthreads();
    }
    if (tid < NBK) {
        int ex = sc[tid] - v;
        lofs[tid] = ex;
        cur[tid] = ex;
        gbase[tid] = atomicAdd(&bcursor[tid], v);  // one reserve per bucket
    }
    if (tid == 0) lofs[NBK] = nE;
    __syncthreads();
    // local place (group by bucket in LDS; edges L2-hot from count pass)
    for (int i = tid; i < nE; i += 512) {
        int s = ei[e0 + i];
        int d = ei[N_EDGES + e0 + i];
        int b = d >> 8;
        int p = atomicAdd(&cur[b], 1);
        stage[p] = ((d & 255) << 17) | s;
    }
    __syncthreads();
    // coalesced run copy-out; bucket of position i via binary search in lofs
    for (int i = tid; i < nE; i += 512) {
        int pv = stage[i];
        int lo = 0, hi = NBK;   // invariant: lofs[lo] <= i < lofs[hi]
        while (hi - lo > 1) {
            int mid = (lo + hi) >> 1;
            if (lofs[mid] <= i) lo = mid; else hi = mid;
        }
        tmp[gbase[lo] + (i - lofs[lo])] = pv;
    }
}

// ---------------- CSR finalize: per-bucket node sort ----------------
__global__ __launch_bounds__(256) void csr_finalize_kernel(
    const int* __restrict__ bstart, const int* __restrict__ tmp,
    int* __restrict__ srcs, int* __restrict__ offsets) {
    __shared__ int cnt[BSZ];
    __shared__ int ofs[BSZ];
    __shared__ int cur[BSZ];
    int b = blockIdx.x, tid = threadIdx.x;
    int beg = bstart[b], end = bstart[b + 1];
    cnt[tid] = 0;
    __syncthreads();
    for (int i = beg + tid; i < end; i += 256)
        atomicAdd(&cnt[tmp[i] >> 17], 1);
    __syncthreads();
    int v = cnt[tid];
    ofs[tid] = v;
    __syncthreads();
    for (int off = 1; off < 256; off <<= 1) {
        int t = (tid >= off) ? ofs[tid - off] : 0;
        __syncthreads();
        ofs[tid] += t;
        __syncthreads();
    }
    int ex = ofs[tid] - v;
    cur[tid] = ex;
    int n = b * BSZ + tid;
    if (n < N_NODES) {
        offsets[n] = beg + ex;
        if (n == N_NODES - 1) offsets[N_NODES] = beg + ex + v;
    }
    __syncthreads();
    for (int i = beg + tid; i < end; i += 256) {
        int pv = tmp[i];
        int p = atomicAdd(&cur[pv >> 17], 1);
        srcs[beg + p] = pv & 0x1FFFF;
    }
}

// ---------------- gather: agg[n] = sum_{e in in(n)} h[src[e]] ----------------
// one wave per node; quad-row float4 scheme: lane group g = j>>4 (0..3) reads
// edge i+g's row as float4 (16 lanes x 16B = 256B), so ONE VMEM instruction
// covers 4 edges (1KB). 2 chains = 8 edges/iter. Final 2-step shfl_xor(16,32)
// folds the 4 groups; group 0 stores the row. Deg-10 node: ~3 wave-loads
// (was ~10) -> 3.3x fewer VMEM issues, 4x bytes per issue.
__global__ __launch_bounds__(256) void gather_kernel(
    const int* __restrict__ offsets, const int* __restrict__ srcs,
    const float* __restrict__ h, float* __restrict__ agg) {
    int w = threadIdx.x >> 6, j = threadIdx.x & 63;
    int n = blockIdx.x * 4 + w;
    if (n >= N_NODES) return;
    int beg = offsets[n], end = offsets[n + 1];
    int g = j >> 4;    // edge-slot within quad
    int c4 = j & 15;   // float4 column
    float4 acc0 = make_float4(0.f, 0.f, 0.f, 0.f);
    float4 acc1 = make_float4(0.f, 0.f, 0.f, 0.f);
    for (int c = beg; c < end; c += 64) {
        int myS = (c + j < end) ? srcs[c + j] : 0;
        int m = min(64, end - c);
        int i = 0;
        for (; i + 7 < m; i += 8) {   // 8 edges via 2 quad-loads
            int sA = __shfl(myS, i + g);
            int sB = __shfl(myS, i + 4 + g);
            float4 vA = *(const float4*)(h + (size_t)sA * HID + c4 * 4);
            float4 vB = *(const float4*)(h + (size_t)sB * HID + c4 * 4);
            acc0.x += vA.x; acc0.y += vA.y; acc0.z += vA.z; acc0.w += vA.w;
            acc1.x += vB.x; acc1.y += vB.y; acc1.z += vB.z; acc1.w += vB.w;
        }
        for (; i < m; i += 4) {       // remainder quads, masked per group
            int e = i + g;
            int ee = (e < m) ? e : 0;
            int sA = __shfl(myS, ee);
            if (e < m) {
                float4 vA = *(const float4*)(h + (size_t)sA * HID + c4 * 4);
                acc0.x += vA.x; acc0.y += vA.y; acc0.z += vA.z; acc0.w += vA.w;
            }
        }
    }
    acc0.x += acc1.x; acc0.y += acc1.y; acc0.z += acc1.z; acc0.w += acc1.w;
    // fold the 4 lane-groups (bits 4,5 of lane id)
    acc0.x += __shfl_xor(acc0.x, 16); acc0.y += __shfl_xor(acc0.y, 16);
    acc0.z += __shfl_xor(acc0.z, 16); acc0.w += __shfl_xor(acc0.w, 16);
    acc0.x += __shfl_xor(acc0.x, 32); acc0.y += __shfl_xor(acc0.y, 32);
    acc0.z += __shfl_xor(acc0.z, 32); acc0.w += __shfl_xor(acc0.w, 32);
    if (g == 0)
        *(float4*)(agg + (size_t)n * HID + c4 * 4) = acc0;
}

// ---------------- fused GIN MLP ----------------
// 256 threads, 64-node tile, 4x4 register micro-tile (16 accs), 49 KB LDS
// -> 3 blocks/CU (12 waves/CU). R9: 400us total, mlp below top-5 cutoff.
__global__ __launch_bounds__(256) void mlp_kernel(
    float* __restrict__ h, const float* __restrict__ agg,
    const float* __restrict__ w1, const float* __restrict__ b1,
    const float* __restrict__ w2, const float* __restrict__ b2) {
    __shared__ float w1s[HID * HID];   // 16 KB
    __shared__ float w2s[HID * HID];   // 16 KB
    __shared__ float ms[64 * MPAD];    // 17 KB, reused for t
    int tid = threadIdx.x;
    int row0 = blockIdx.x * 64;
    for (int i = tid; i < HID * HID / 4; i += 256) {
        ((float4*)w1s)[i] = ((const float4*)w1)[i];
        ((float4*)w2s)[i] = ((const float4*)w2)[i];
    }
#pragma unroll
    for (int i = 0; i < 4; i++) {
        int f = tid + i * 256;
        int r = f >> 4, c4 = f & 15;
        int n = row0 + r;
        float4 mv = make_float4(0.f, 0.f, 0.f, 0.f);
        if (n < N_NODES) {
            float4 h4 = ((const float4*)(h + (size_t)n * HID))[c4];
            float4 a4 = ((const float4*)(agg + (size_t)n * HID))[c4];
            mv = make_float4(h4.x + a4.x, h4.y + a4.y, h4.z + a4.z, h4.w + a4.w);
        }
        *(float4*)&ms[r * MPAD + c4 * 4] = mv;
    }
    __syncthreads();

    int ty = tid >> 4, tx = tid & 15;   // ty 0..15, tx 0..15
    int r0 = ty * 4, c0 = tx * 4;

    float4 a0, a1, a2, a3;
#define GEMM_LDS(WS)                                                          \
    do {                                                                      \
        a0 = make_float4(0.f, 0.f, 0.f, 0.f); a1 = a0; a2 = a0; a3 = a0;      \
        _Pragma("unroll 4")                                                   \
        for (int k0 = 0; k0 < HID; k0 += 4) {                                 \
            float4 m0 = *(const float4*)&ms[(r0 + 0) * MPAD + k0];            \
            float4 m1 = *(const float4*)&ms[(r0 + 1) * MPAD + k0];            \
            float4 m2 = *(const float4*)&ms[(r0 + 2) * MPAD + k0];            \
            float4 m3 = *(const float4*)&ms[(r0 + 3) * MPAD + k0];            \
            float4 w0 = *(const float4*)&WS[(k0 + 0) * HID + c0];             \
            float4 w1v = *(const float4*)&WS[(k0 + 1) * HID + c0];            \
            float4 w2v = *(const float4*)&WS[(k0 + 2) * HID + c0];            \
            float4 w3v = *(const float4*)&WS[(k0 + 3) * HID + c0];            \
            a0.x += m0.x * w0.x + m0.y * w1v.x + m0.z * w2v.x + m0.w * w3v.x; \
            a0.y += m0.x * w0.y + m0.y * w1v.y + m0.z * w2v.y + m0.w * w3v.y; \
            a0.z += m0.x * w0.z + m0.y * w1v.z + m0.z * w2v.z + m0.w * w3v.z; \
            a0.w += m0.x * w0.w + m0.y * w1v.w + m0.z * w2v.w + m0.w * w3v.w; \
            a1.x += m1.x * w0.x + m1.y * w1v.x + m1.z * w2v.x + m1.w * w3v.x; \
            a1.y += m1.x * w0.y + m1.y * w1v.y + m1.z * w2v.y + m1.w * w3v.y; \
            a1.z += m1.x * w0.z + m1.y * w1v.z + m1.z * w2v.z + m1.w * w3v.z; \
            a1.w += m1.x * w0.w + m1.y * w1v.w + m1.z * w2v.w + m1.w * w3v.w; \
            a2.x += m2.x * w0.x + m2.y * w1v.x + m2.z * w2v.x + m2.w * w3v.x; \
            a2.y += m2.x * w0.y + m2.y * w1v.y + m2.z * w2v.y + m2.w * w3v.y; \
            a2.z += m2.x * w0.z + m2.y * w1v.z + m2.z * w2v.z + m2.w * w3v.z; \
            a2.w += m2.x * w0.w + m2.y * w1v.w + m2.z * w2v.w + m2.w * w3v.w; \
            a3.x += m3.x * w0.x + m3.y * w1v.x + m3.z * w2v.x + m3.w * w3v.x; \
            a3.y += m3.x * w0.y + m3.y * w1v.y + m3.z * w2v.y + m3.w * w3v.y; \
            a3.z += m3.x * w0.z + m3.y * w1v.z + m3.z * w2v.z + m3.w * w3v.z; \
            a3.w += m3.x * w0.w + m3.y * w1v.w + m3.z * w2v.w + m3.w * w3v.w; \
        }                                                                     \
    } while (0)

    GEMM_LDS(w1s);  // GEMM1

    float4 bv1 = *(const float4*)&b1[c0];
    float4 t0 = make_float4(fmaxf(a0.x + bv1.x, 0.f), fmaxf(a0.y + bv1.y, 0.f),
                            fmaxf(a0.z + bv1.z, 0.f), fmaxf(a0.w + bv1.w, 0.f));
    float4 t1 = make_float4(fmaxf(a1.x + bv1.x, 0.f), fmaxf(a1.y + bv1.y, 0.f),
                            fmaxf(a1.z + bv1.z, 0.f), fmaxf(a1.w + bv1.w, 0.f));
    float4 t2 = make_float4(fmaxf(a2.x + bv1.x, 0.f), fmaxf(a2.y + bv1.y, 0.f),
                            fmaxf(a2.z + bv1.z, 0.f), fmaxf(a2.w + bv1.w, 0.f));
    float4 t3 = make_float4(fmaxf(a3.x + bv1.x, 0.f), fmaxf(a3.y + bv1.y, 0.f),
                            fmaxf(a3.z + bv1.z, 0.f), fmaxf(a3.w + bv1.w, 0.f));

    __syncthreads();  // all GEMM1 reads of ms complete
    *(float4*)&ms[(r0 + 0) * MPAD + c0] = t0;
    *(float4*)&ms[(r0 + 1) * MPAD + c0] = t1;
    *(float4*)&ms[(r0 + 2) * MPAD + c0] = t2;
    *(float4*)&ms[(r0 + 3) * MPAD + c0] = t3;
    __syncthreads();

    GEMM_LDS(w2s);  // GEMM2

    float4 bv2 = *(const float4*)&b2[c0];
#pragma unroll
    for (int i = 0; i < 4; i++) {
        int n = row0 + r0 + i;
        if (n < N_NODES) {
            float4 av = (i == 0) ? a0 : (i == 1) ? a1 : (i == 2) ? a2 : a3;
            float4 hold = *(const float4*)(h + (size_t)n * HID + c0);
            float4 o;
            o.x = fmaxf(av.x + bv2.x, 0.f) + hold.x;
            o.y = fmaxf(av.y + bv2.y, 0.f) + hold.y;
            o.z = fmaxf(av.z + bv2.z, 0.f) + hold.z;
            o.w = fmaxf(av.w + bv2.w, 0.f) + hold.w;
            *(float4*)(h + (size_t)n * HID + c0) = o;
        }
    }
#undef GEMM_LDS
}

// ---------------- global add pool ----------------
__global__ __launch_bounds__(256) void pool_kernel(
    const float* __restrict__ h, const int* __restrict__ batch,
    float* __restrict__ pooled) {
    int tid = threadIdx.x;
    int w = tid >> 6, j = tid & 63;
    int n0 = blockIdx.x * 256 + w * 64;
    if (n0 >= N_NODES) return;
    int nend = min(n0 + 64, N_NODES);
    float acc = 0.f;
    int cur = batch[n0];
    for (int n = n0; n < nend; n++) {
        int b = batch[n];
        if (b != cur) {
            atomicAdd(&pooled[cur * HID + j], acc);
            acc = 0.f;
            cur = b;
        }
        acc += h[(size_t)n * HID + j];
    }
    atomicAdd(&pooled[cur * HID + j], acc);
}

// ---------------- final FC ----------------
__global__ __launch_bounds__(256) void final_kernel(
    const float* __restrict__ pooled, const float* __restrict__ w_fc,
    const float* __restrict__ b_fc, float* __restrict__ out) {
    int gid = blockIdx.x * 256 + threadIdx.x;
    if (gid >= N_GRAPHS * LAT) return;
    int g = gid >> 5, j = gid & 31;
    float acc = b_fc[j];
#pragma unroll
    for (int k = 0; k < HID; k++)
        acc += pooled[g * HID + k] * w_fc[k * LAT + j];
    out[gid] = acc;
}

extern "C" void kernel_launch(void* const* d_in, const int* in_sizes, int n_in,
                              void* d_out, int out_size, void* d_ws,
                              size_t ws_size, hipStream_t stream) {
    const float* x     = (const float*)d_in[0];
    const int*   ei    = (const int*)d_in[1];
    const int*   batch = (const int*)d_in[2];
    const float* w_in  = (const float*)d_in[3];
    const float* b_in  = (const float*)d_in[4];
    const float* w1    = (const float*)d_in[5];
    const float* b1    = (const float*)d_in[6];
    const float* w2    = (const float*)d_in[7];
    const float* b2    = (const float*)d_in[8];
    const float* w_fc  = (const float*)d_in[9];
    const float* b_fc  = (const float*)d_in[10];
    float* out = (float*)d_out;

    // persistent: h | agg | pooled | offsets | srcs   (~55.6 MB)
    float* h       = (float*)d_ws;
    float* agg     = h + (size_t)N_NODES * HID;
    float* pooled  = agg + (size_t)N_NODES * HID;
    int*   offsets = (int*)(pooled + N_GRAPHS * HID);   // N_NODES+1
    int*   srcs    = offsets + (N_NODES + 2);           // N_EDGES
    // build-time arrays overlaid into agg's region (dead before first gather)
    int* tmp     = (int*)agg;            // N_EDGES packed bucket-major edges
    int* bhist   = tmp + N_EDGES;        // NBK
    int* bstart  = bhist + NBK;          // NBK + 1
    int* bcursor = bstart + (NBK + 1);   // NBK

    proj_kernel<<<(N_NODES + 3) / 4, 256, 0, stream>>>(x, w_in, b_in, h);

    // coalesced CSR build (once; edges constant across layers)
    hipMemsetAsync(bhist, 0, NBK * sizeof(int), stream);
    bhist_kernel<<<(N_EDGES + 4095) / 4096, 256, 0, stream>>>(ei, bhist);
    bscan_kernel<<<1, 512, 0, stream>>>(bhist, bstart, bcursor);
    binsort_kernel<<<NBIN_BLOCKS, 512, 0, stream>>>(ei, bcursor, tmp);
    csr_finalize_kernel<<<NBK, 256, 0, stream>>>(bstart, tmp, srcs, offsets);

    for (int i = 0; i < N_LAYERS; i++) {
        gather_kernel<<<(N_NODES + 3) / 4, 256, 0, stream>>>(offsets, srcs, h, agg);
        mlp_kernel<<<(N_NODES + 63) / 64, 256, 0, stream>>>(
            h, agg, w1 + (size_t)i * HID * HID, b1 + (size_t)i * HID,
            w2 + (size_t)i * HID * HID, b2 + (size_t)i * HID);
    }

    hipMemsetAsync(pooled, 0, N_GRAPHS * HID * sizeof(float), stream);
    pool_kernel<<<(N_NODES + 255) / 256, 256, 0, stream>>>(h, batch, pooled);
    final_kernel<<<(N_GRAPHS * LAT + 255) / 256, 256, 0, stream>>>(
        pooled, w_fc, b_fc, out);
}